// Round 9
// baseline (595.905 us; speedup 1.0000x reference)
//
#include <hip/hip_runtime.h>

// ---------------------------------------------------------------------------
// StaNet PAM — round 9: MFMA attention (32x32x16 bf16), fragment-order V.
// Inputs fp32 insertion-order (proven r5/r6), output fp32 (proven r6).
// Unnormalized ctx + lsum merged across key-split WGs via atomicAdd (proven
// r8); normconv divides and applies the final 1x1 conv.
//
// Workspace:
//   Qb  @ ush 0       : 262144 ush  [st][blk][p][ch] bf16, pre-scaled QMUL
//   Kb  @ ush 262144  : 262144 ush  [st][blk][p][ch] bf16
//   Vf  @ ush 524288  : 2097152 ush [st][blk][chunk64][kc4][chalf2][lane64][j8]
//   CTXU@ fl  1310720 : 2097152 fl  canonical [st][c][pix]  (atomics)
//   LSUM@ fl  3407872 : 32768 fl    [st][pix]               (atomics)
// Total 13.1 MB. pix = half*4096 + h*64 + w.
// Block decode: hb=6-st, si=blk>>st, sj=blk&((1<<st)-1);
// block-point p: half=p&1, pw=p>>1, wi=pw&wlm, hi=pw>>hb.
// MFMA layouts (guide §3, 32x32x16 bf16):
//   A[m][k]: m=lane&31, k=8*(lane>>5)+j   (8 bf16/lane)
//   B[k][n]: n=lane&31, k=8*(lane>>5)+j
//   C/D:     col=lane&31, row=(reg&3)+8*(reg>>2)+4*(lane>>5), reg in [0,16)
// ---------------------------------------------------------------------------

typedef short bf16x8 __attribute__((ext_vector_type(8)));
typedef float f32x16 __attribute__((ext_vector_type(16)));

__device__ __forceinline__ float bf2f(unsigned short u){ union{unsigned int i;float f;}v; v.i=((unsigned int)u)<<16; return v.f; }
__device__ __forceinline__ unsigned short f2bf(float f){
    union{float f;unsigned int i;}v; v.f=f;
    unsigned int r = v.i + 0x7fffu + ((v.i>>16)&1u);
    return (unsigned short)(r>>16);
}
__device__ __forceinline__ void atomAdd(float* p, float v){
#if __has_builtin(__builtin_amdgcn_global_atomic_fadd_f32)
    unsafeAtomicAdd(p, v);
#else
    atomicAdd(p, v);
#endif
}
__device__ __forceinline__ float exp2fast(float x){ return __builtin_amdgcn_exp2f(x); }

// 8^-0.5 * log2(e): folded into Q so softmax weight = exp2(q'.k)
#define QMUL 0.5100697233f

// Kernel 0: zero CTXU + LSUM (2129920 floats = 532480 float4 = 2080 x 256).
__global__ __launch_bounds__(256) void zero_kernel(float4* __restrict__ p){
    p[blockIdx.x*256 + threadIdx.x] = float4{0.f,0.f,0.f,0.f};
}

// ---------------------------------------------------------------------------
// Kernel 1: projections -> blocked bf16 layouts. One WG per (stage, ch) = 320.
// ---------------------------------------------------------------------------
__global__ __launch_bounds__(256) void proj_kernel(
    const float* __restrict__ x1, const float* __restrict__ x2,
    const float* __restrict__ Wq, const float* __restrict__ bq,
    const float* __restrict__ gq, const float* __restrict__ beq,
    const float* __restrict__ Wk, const float* __restrict__ bk,
    const float* __restrict__ gk, const float* __restrict__ bek,
    const float* __restrict__ Wv, const float* __restrict__ bv,
    unsigned short* __restrict__ Qb, unsigned short* __restrict__ Kb,
    unsigned short* __restrict__ Vf)
{
    const int o = blockIdx.x, st = o/80, c = o%80;
    const int hb = 6-st, wlm = (1<<hb)-1, P = 8192>>(2*st);

    const float* W; int base; float scale, bias; int mode, ch;
    if (c < 8) {
        ch = c; W = Wq; base = (st*8+ch)*64;
        float g = gq[st*8+ch];
        scale = g*QMUL; bias = (g*bq[st*8+ch] + beq[st*8+ch])*QMUL; mode = 0;
    } else if (c < 16) {
        ch = c-8; W = Wk; base = (st*8+ch)*64;
        float g = gk[st*8+ch];
        scale = g; bias = g*bk[st*8+ch] + bek[st*8+ch]; mode = 1;
    } else {
        ch = c-16; W = Wv; base = (st*64+ch)*64;
        scale = 1.f; bias = bv[st*64+ch]; mode = 2;
    }

    float wr[64];
    #pragma unroll
    for (int k = 0; k < 64; ++k) wr[k] = W[base+k];

    for (int it = 0; it < 32; ++it) {
        int px = it*256 + threadIdx.x;
        int half = px >> 12, hw = px & 4095;
        const float* src = half ? x2 : x1;
        float acc = 0.f;
        #pragma unroll
        for (int k = 0; k < 64; ++k) acc += wr[k]*src[k*4096 + hw];
        float val = scale*acc + bias;
        unsigned short vb = f2bf(val);

        int h = hw >> 6, w = hw & 63;
        int si = h >> hb, sj = w >> hb, hi = h & wlm, wi = w & wlm;
        int blk = (si << st) | sj;
        int p = (((hi << hb) | wi) << 1) | half;
        if (mode == 0) {
            Qb[st*65536 + blk*P*8 + p*8 + ch] = vb;
        } else if (mode == 1) {
            Kb[st*65536 + blk*P*8 + p*8 + ch] = vb;
        } else {
            int k = p & 63;
            Vf[st*524288 + blk*P*64 + (p>>6)*4096
               + (k>>4)*1024 + (ch>>5)*512
               + ((((k>>3)&1)<<5) | (ch&31))*8 + (k&7)] = vb;
        }
    }
}

// ---------------------------------------------------------------------------
// Kernel 2: MFMA flash attention. 960 WGs x 256 threads (4 waves).
//   wg<512 : st0 (blk 0):        q0=(wg>>3)*128, kbase=(wg&7)*1024, nk=1024
//   wg<768 : st1: r=wg-512: blk=r>>6, r2=r&63, q0=(r2>>2)*128, kbase=(r2&3)*512
//   wg<896 : st2: r=wg-768: blk=r>>3, r2=r&7,  q0=(r2>>1)*128, kbase=(r2&1)*256
//   else   : st3: blk=wg-896, q0=0, kbase=0, nk=128
// Each wave owns a 32-query tile; K/V chunks staged WG-wide.
// ---------------------------------------------------------------------------
__global__ __launch_bounds__(256) void attn_kernel(
    const unsigned short* __restrict__ Qb, const unsigned short* __restrict__ Kb,
    const unsigned short* __restrict__ Vf,
    float* __restrict__ CTXU, float* __restrict__ LSUM)
{
    __shared__ __align__(16) unsigned short Ks[512];        // [key64][ch8]
    __shared__ __align__(16) unsigned short Vs[4096];       // frag-order 8KB
    __shared__ __align__(16) unsigned short Ps[4][2048];    // per-wave [q32][k64]

    const int wg = blockIdx.x;
    int st, blk, q0, kbase, nk;
    if (wg < 512)      { st=0; blk=0;            q0=(wg>>3)*128;      kbase=(wg&7)*1024;  nk=1024; }
    else if (wg < 768) { int r=wg-512; st=1; blk=r>>6; int r2=r&63; q0=(r2>>2)*128; kbase=(r2&3)*512; nk=512; }
    else if (wg < 896) { int r=wg-768; st=2; blk=r>>3; int r2=r&7;  q0=(r2>>1)*128; kbase=(r2&1)*256; nk=256; }
    else               { st=3; blk=wg-896;       q0=0;               kbase=0;            nk=128; }

    const int P = 8192 >> (2*st), hb = 6-st, wlm = (1<<hb)-1;
    const int si = blk >> st, sj = blk & ((1<<st)-1);
    const int t = threadIdx.x, lane = t & 63, wv = t >> 6;
    const int l31 = lane & 31, lhi = lane >> 5;

    const unsigned short* Qg = Qb + st*65536 + blk*P*8;
    const unsigned short* Kg = Kb + st*65536 + blk*P*8;
    const unsigned short* Vg = Vf + st*524288 + blk*P*64;

    // Q A-frag: lane<32 holds Q[q=l31][c=0..7]; lanes>=32 are the zero pad.
    bf16x8 qa;
    #pragma unroll
    for (int j = 0; j < 8; ++j) qa[j] = 0;
    if (lane < 32) qa = *(const bf16x8*)(Qg + (q0 + wv*32 + l31)*8);

    f32x16 acc0, acc1;
    #pragma unroll
    for (int r = 0; r < 16; ++r) { acc0[r] = 0.f; acc1[r] = 0.f; }
    float lsum_reg = 0.f;

    for (int k0 = kbase; k0 < kbase + nk; k0 += 64) {
        __syncthreads();
        if (t < 64) ((uint4*)Ks)[t] = ((const uint4*)(Kg + k0*8))[t];
        {
            const uint4* vsrc = (const uint4*)(Vg + (k0>>6)*4096);
            ((uint4*)Vs)[t]       = vsrc[t];
            ((uint4*)Vs)[t+256]   = vsrc[t+256];
        }
        __syncthreads();

        // QK^T -> S[32q x 64k] in two 32k halves
        bf16x8 kb0 = *(const bf16x8*)(Ks + l31*8);          // keys 0..31
        bf16x8 kb1 = *(const bf16x8*)(Ks + (32 + l31)*8);   // keys 32..63
        f32x16 S0, S1;
        #pragma unroll
        for (int r = 0; r < 16; ++r) { S0[r] = 0.f; S1[r] = 0.f; }
        S0 = __builtin_amdgcn_mfma_f32_32x32x16_bf16(qa, kb0, S0, 0, 0, 0);
        S1 = __builtin_amdgcn_mfma_f32_32x32x16_bf16(qa, kb1, S1, 0, 0, 0);

        // exp2 (QMUL pre-folded) -> bf16 -> Ps[q][k]
        unsigned short* Pw = Ps[wv];
        #pragma unroll
        for (int r = 0; r < 16; ++r) {
            int qrow = (r&3) + 8*(r>>2) + 4*lhi;
            Pw[qrow*64 + l31]      = f2bf(exp2fast(S0[r]));
            Pw[qrow*64 + 32 + l31] = f2bf(exp2fast(S1[r]));
        }

        // P A-frags + lsum (sum of the SAME bf16 P used in PV -> consistent)
        float lpart = 0.f;
        bf16x8 pa[4];
        #pragma unroll
        for (int kc = 0; kc < 4; ++kc) {
            pa[kc] = *(const bf16x8*)(Pw + l31*64 + kc*16 + 8*lhi);
            #pragma unroll
            for (int j = 0; j < 8; ++j)
                lpart += bf2f((unsigned short)pa[kc][j]);
        }
        lpart += __shfl_xor(lpart, 32, 64);
        lsum_reg += lpart;

        // PV: ctx[32q x 64c] += P[32q x 16k] * V[16k x 32c]  (x4 kc, x2 chalf)
        #pragma unroll
        for (int kc = 0; kc < 4; ++kc) {
            bf16x8 vb0 = *(const bf16x8*)(Vs + ((kc*2+0)*64 + lane)*8);
            bf16x8 vb1 = *(const bf16x8*)(Vs + ((kc*2+1)*64 + lane)*8);
            acc0 = __builtin_amdgcn_mfma_f32_32x32x16_bf16(pa[kc], vb0, acc0, 0, 0, 0);
            acc1 = __builtin_amdgcn_mfma_f32_32x32x16_bf16(pa[kc], vb1, acc1, 0, 0, 0);
        }
    }

    // epilogue: atomic-merge unnormalized ctx + lsum
    int qpix[16];
    #pragma unroll
    for (int r = 0; r < 16; ++r) {
        int qrow = (r&3) + 8*(r>>2) + 4*lhi;
        int p = q0 + wv*32 + qrow;
        int half = p & 1, pw = p >> 1;
        qpix[r] = (half<<12) + (((si<<hb)|(pw>>hb))<<6) + ((sj<<hb)|(pw&wlm));
    }
    float* Cst = CTXU + st*524288;
    #pragma unroll
    for (int r = 0; r < 16; ++r) {
        atomAdd(Cst + l31*8192      + qpix[r], acc0[r]);
        atomAdd(Cst + (32+l31)*8192 + qpix[r], acc1[r]);
    }
    if (lane < 32) {
        int p = q0 + wv*32 + l31;
        int half = p & 1, pw = p >> 1;
        int pixq = (half<<12) + (((si<<hb)|(pw>>hb))<<6) + ((sj<<hb)|(pw&wlm));
        atomAdd(LSUM + st*8192 + pixq, lsum_reg);
    }
}

// ---------------------------------------------------------------------------
// Kernel 3: normalize ctx by lsum + final 1x1 conv (256->64). 256 WGs.
// ---------------------------------------------------------------------------
__global__ __launch_bounds__(256) void normconv_kernel(
    const float* __restrict__ CTXU, const float* __restrict__ LSUM,
    const float* __restrict__ Wo, float* __restrict__ out)
{
    __shared__ float cs[256][33];
    __shared__ float linv[4][32];
    const int t = threadIdx.x;
    const int px0 = blockIdx.x * 32;

    if (t < 128) {
        int stt = t >> 5, i = t & 31;
        linv[stt][i] = 1.f / LSUM[stt*8192 + px0 + i];
    }
    __syncthreads();
    for (int idx = t; idx < 256*32; idx += 256) {
        int d = idx >> 5, i = idx & 31;        // d = st*64 + cv
        int stt = d >> 6, cv = d & 63;
        cs[d][i] = CTXU[stt*524288 + cv*8192 + px0 + i] * linv[stt][i];
    }
    __syncthreads();

    const int i = t & 31;
    const int pix = px0 + i;
    const int half = pix >> 12, hw = pix & 4095;
    float* obase = out + half*262144 + hw;
    for (int oc = (t >> 5); oc < 64; oc += 8) {
        const float* wp = Wo + oc*256;
        float accv = 0.f;
        #pragma unroll 8
        for (int d = 0; d < 256; ++d) accv += wp[d]*cs[d][i];
        obase[oc*4096] = accv;
    }
}

// ---------------------------------------------------------------------------
extern "C" void kernel_launch(void* const* d_in, const int* in_sizes, int n_in,
                              void* d_out, int out_size, void* d_ws, size_t ws_size,
                              hipStream_t stream)
{
    (void)out_size; (void)ws_size;
    const float *x1, *x2, *Wq, *bq, *gq, *beq, *Wk, *bk, *gk, *bek, *Wv, *bv, *Wo;

    if (n_in >= 13 && in_sizes[0] == 2048) {       // sorted-key order (insurance)
        Wk  = (const float*)d_in[0];  Wo  = (const float*)d_in[1];
        Wq  = (const float*)d_in[2];  Wv  = (const float*)d_in[3];
        bek = (const float*)d_in[4];  beq = (const float*)d_in[5];
        bk  = (const float*)d_in[6];  bq  = (const float*)d_in[7];
        bv  = (const float*)d_in[8];  gk  = (const float*)d_in[9];
        gq  = (const float*)d_in[10];
        x1  = (const float*)d_in[11]; x2  = (const float*)d_in[12];
    } else {                                        // insertion order (proven)
        x1  = (const float*)d_in[0];  x2  = (const float*)d_in[1];
        Wq  = (const float*)d_in[2];  bq  = (const float*)d_in[3];
        gq  = (const float*)d_in[4];  beq = (const float*)d_in[5];
        Wk  = (const float*)d_in[6];  bk  = (const float*)d_in[7];
        gk  = (const float*)d_in[8];  bek = (const float*)d_in[9];
        Wv  = (const float*)d_in[10]; bv  = (const float*)d_in[11];
        Wo  = (const float*)d_in[12];
    }

    unsigned short* Qb = (unsigned short*)d_ws;     // 262144 ush
    unsigned short* Kb = Qb + 262144;               // 262144 ush
    unsigned short* Vf = Kb + 262144;               // 2097152 ush
    float* Cw = (float*)d_ws + 1310720;             // 2097152 fl
    float* Lw = Cw + 2097152;                       // 32768 fl

    zero_kernel<<<2080, 256, 0, stream>>>((float4*)Cw);
    proj_kernel<<<320, 256, 0, stream>>>(x1,x2,Wq,bq,gq,beq,Wk,bk,gk,bek,Wv,bv,Qb,Kb,Vf);
    attn_kernel<<<960, 256, 0, stream>>>(Qb,Kb,Vf,Cw,Lw);
    normconv_kernel<<<256, 256, 0, stream>>>(Cw, Lw, Wo, (float*)d_out);
}

// Round 10
// 469.297 us; speedup vs baseline: 1.2698x; 1.2698x over previous
//
#include <hip/hip_runtime.h>

// ---------------------------------------------------------------------------
// StaNet PAM — round 10: fix proj's scattered 2B stores (r9 regression).
// Q/K: [st][gp][ch] bf16 (16B per point, written as one uint4 per thread).
// V:   [st][blk][ch][p] bf16 (coalesced stores); attn staging does the
//      fragment swizzle with 16B reads + 16B LDS writes.
// MFMA attention core identical to r9 (passed, absmax 6.1e-5).
//
// Workspace:
//   Qb  @ ush 0       : 262144 ush
//   Kb  @ ush 262144  : 262144 ush
//   Vf  @ ush 524288  : 2097152 ush
//   CTXU@ fl  1310720 : 2097152 fl  canonical [st][c][pix] (atomics)
//   LSUM@ fl  3407872 : 32768 fl    [st][pix]              (atomics)
// Total 13.1 MB. pix = half*4096 + h*64 + w. gp = blk*P + p.
// ---------------------------------------------------------------------------

typedef short bf16x8 __attribute__((ext_vector_type(8)));
typedef float f32x16 __attribute__((ext_vector_type(16)));

__device__ __forceinline__ float bf2f(unsigned short u){ union{unsigned int i;float f;}v; v.i=((unsigned int)u)<<16; return v.f; }
__device__ __forceinline__ unsigned short f2bf(float f){
    union{float f;unsigned int i;}v; v.f=f;
    unsigned int r = v.i + 0x7fffu + ((v.i>>16)&1u);
    return (unsigned short)(r>>16);
}
__device__ __forceinline__ void atomAdd(float* p, float v){
#if __has_builtin(__builtin_amdgcn_global_atomic_fadd_f32)
    unsafeAtomicAdd(p, v);
#else
    atomicAdd(p, v);
#endif
}
__device__ __forceinline__ float exp2fast(float x){ return __builtin_amdgcn_exp2f(x); }

#define QMUL 0.5100697233f   // 8^-0.5 * log2(e), folded into Q

// Kernel 0: zero CTXU + LSUM (2129920 floats = 532480 float4 = 2080 x 256).
__global__ __launch_bounds__(256) void zero_kernel(float4* __restrict__ p){
    p[blockIdx.x*256 + threadIdx.x] = float4{0.f,0.f,0.f,0.f};
}

// ---------------------------------------------------------------------------
// Kernel 1a: Q+K projections. 64 WGs (4 st x 16 chunks of 512 gp).
// Thread: 2 gp points; x[64] in VGPRs, weights wave-uniform (SGPR), one
// 16B store per tensor per point.
// ---------------------------------------------------------------------------
__global__ __launch_bounds__(256) void proj_qk_kernel(
    const float* __restrict__ x1, const float* __restrict__ x2,
    const float* __restrict__ Wq, const float* __restrict__ bq,
    const float* __restrict__ gq, const float* __restrict__ beq,
    const float* __restrict__ Wk, const float* __restrict__ bk,
    const float* __restrict__ gk, const float* __restrict__ bek,
    unsigned short* __restrict__ Qb, unsigned short* __restrict__ Kb)
{
    const int wg = blockIdx.x, st = wg >> 4, chunk = wg & 15;
    const int lgP = 13 - 2*st, Pm1 = (1<<lgP) - 1;
    const int hb = 6 - st, wlm = (1<<hb) - 1;
    const int t = threadIdx.x;

    for (int rep = 0; rep < 2; ++rep) {
        int gp = chunk*512 + rep*256 + t;
        int blk = gp >> lgP, p = gp & Pm1;
        int si = blk >> st, sj = blk & ((1<<st)-1);
        int half = p & 1, pw = p >> 1;
        int hw = ((((si<<hb)|(pw>>hb))<<6)) | ((sj<<hb)|(pw&wlm));
        const float* src = half ? x2 : x1;

        float xr[64];
        #pragma unroll
        for (int k = 0; k < 64; ++k) xr[k] = src[k*4096 + hw];

        unsigned short qo[8], ko[8];
        for (int ch = 0; ch < 8; ++ch) {          // not unrolled: SGPR weights/ch
            const float* wp = Wq + (st*8 + ch)*64;
            float d = 0.f;
            #pragma unroll
            for (int k = 0; k < 64; ++k) d += wp[k]*xr[k];
            float g = gq[st*8+ch];
            qo[ch] = f2bf((g*d + g*bq[st*8+ch] + beq[st*8+ch])*QMUL);

            const float* wp2 = Wk + (st*8 + ch)*64;
            float d2 = 0.f;
            #pragma unroll
            for (int k = 0; k < 64; ++k) d2 += wp2[k]*xr[k];
            float g2 = gk[st*8+ch];
            ko[ch] = f2bf(g2*d2 + g2*bk[st*8+ch] + bek[st*8+ch]);
        }
        *(uint4*)(Qb + st*65536 + gp*8) = *(uint4*)qo;
        *(uint4*)(Kb + st*65536 + gp*8) = *(uint4*)ko;
    }
}

// ---------------------------------------------------------------------------
// Kernel 1b: V projection. 512 WGs (4 st x 64 ch x 2 half-ranges).
// Thread streams 16 gp; stores coalesced bf16 (128B per wave-store).
// ---------------------------------------------------------------------------
__global__ __launch_bounds__(256) void proj_v_kernel(
    const float* __restrict__ x1, const float* __restrict__ x2,
    const float* __restrict__ Wv, const float* __restrict__ bv,
    unsigned short* __restrict__ Vf)
{
    const int wg = blockIdx.x;
    const int st = wg >> 7, r = wg & 127, ch = r >> 1, pc = r & 1;
    const int lgP = 13 - 2*st, Pm1 = (1<<lgP) - 1;
    const int hb = 6 - st, wlm = (1<<hb) - 1;
    const int t = threadIdx.x;

    float wr[64];
    #pragma unroll
    for (int k = 0; k < 64; ++k) wr[k] = Wv[(st*64 + ch)*64 + k];
    const float bias = bv[st*64 + ch];

    unsigned short* Vst = Vf + st*524288;
    for (int it = 0; it < 16; ++it) {
        int gp = pc*4096 + it*256 + t;
        int blk = gp >> lgP, p = gp & Pm1;
        int si = blk >> st, sj = blk & ((1<<st)-1);
        int half = p & 1, pw = p >> 1;
        int hw = ((((si<<hb)|(pw>>hb))<<6)) | ((sj<<hb)|(pw&wlm));
        const float* src = half ? x2 : x1;
        float acc = bias;
        #pragma unroll
        for (int k = 0; k < 64; ++k) acc += wr[k]*src[k*4096 + hw];
        Vst[(blk << (lgP+6)) + (ch << lgP) + p] = f2bf(acc);
    }
}

// ---------------------------------------------------------------------------
// Kernel 2: MFMA flash attention. 960 WGs x 256 threads (4 waves).
//   wg<512 : st0 (blk 0):        q0=(wg>>3)*128, kbase=(wg&7)*1024, nk=1024
//   wg<768 : st1: r=wg-512: blk=r>>6, r2=r&63, q0=(r2>>2)*128, kbase=(r2&3)*512
//   wg<896 : st2: r=wg-768: blk=r>>3, r2=r&7,  q0=(r2>>1)*128, kbase=(r2&1)*256
//   else   : st3: blk=wg-896, q0=0, kbase=0, nk=128
// V staged from [ch][p] global into fragment-order LDS (16B-granule both ways).
// MFMA layouts (32x32x16 bf16): A[m][k]: m=lane&31, k=8*(lane>>5)+j;
// B[k][n]: n=lane&31; C/D: col=lane&31, row=(reg&3)+8*(reg>>2)+4*(lane>>5).
// ---------------------------------------------------------------------------
__global__ __launch_bounds__(256) void attn_kernel(
    const unsigned short* __restrict__ Qb, const unsigned short* __restrict__ Kb,
    const unsigned short* __restrict__ Vf,
    float* __restrict__ CTXU, float* __restrict__ LSUM)
{
    __shared__ __align__(16) unsigned short Ks[512];        // [key64][ch8]
    __shared__ __align__(16) unsigned short Vs[4096];       // frag-order 8KB
    __shared__ __align__(16) unsigned short Ps[4][2048];    // per-wave [q32][k64]

    const int wg = blockIdx.x;
    int st, blk, q0, kbase, nk;
    if (wg < 512)      { st=0; blk=0;            q0=(wg>>3)*128;      kbase=(wg&7)*1024;  nk=1024; }
    else if (wg < 768) { int r=wg-512; st=1; blk=r>>6; int r2=r&63; q0=(r2>>2)*128; kbase=(r2&3)*512; nk=512; }
    else if (wg < 896) { int r=wg-768; st=2; blk=r>>3; int r2=r&7;  q0=(r2>>1)*128; kbase=(r2&1)*256; nk=256; }
    else               { st=3; blk=wg-896;       q0=0;               kbase=0;            nk=128; }

    const int P = 8192 >> (2*st), hb = 6-st, wlm = (1<<hb)-1;
    const int si = blk >> st, sj = blk & ((1<<st)-1);
    const int t = threadIdx.x, lane = t & 63, wv = t >> 6;
    const int l31 = lane & 31, lhi = lane >> 5;

    const unsigned short* Qg = Qb + st*65536 + blk*P*8;
    const unsigned short* Kg = Kb + st*65536 + blk*P*8;
    const unsigned short* Vg = Vf + st*524288 + blk*P*64;   // [ch][p]

    bf16x8 qa;
    #pragma unroll
    for (int j = 0; j < 8; ++j) qa[j] = 0;
    if (lane < 32) qa = *(const bf16x8*)(Qg + (q0 + wv*32 + l31)*8);

    f32x16 acc0, acc1;
    #pragma unroll
    for (int r = 0; r < 16; ++r) { acc0[r] = 0.f; acc1[r] = 0.f; }
    float lsum_reg = 0.f;

    for (int k0 = kbase; k0 < kbase + nk; k0 += 64) {
        __syncthreads();
        if (t < 64) ((uint4*)Ks)[t] = ((const uint4*)(Kg + k0*8))[t];
        // V fragment swizzle: task = (ch, key-octet o); 16B read, 16B write.
        #pragma unroll
        for (int r = 0; r < 2; ++r) {
            int task = t + r*256;
            int ch = task >> 3, o = task & 7;
            uint4 v = *(const uint4*)(Vg + ch*P + k0 + o*8);
            *(uint4*)(Vs + (o>>1)*1024 + (ch>>5)*512 + ((((o&1)<<5) | (ch&31)))*8) = v;
        }
        __syncthreads();

        bf16x8 kb0 = *(const bf16x8*)(Ks + l31*8);
        bf16x8 kb1 = *(const bf16x8*)(Ks + (32 + l31)*8);
        f32x16 S0, S1;
        #pragma unroll
        for (int r = 0; r < 16; ++r) { S0[r] = 0.f; S1[r] = 0.f; }
        S0 = __builtin_amdgcn_mfma_f32_32x32x16_bf16(qa, kb0, S0, 0, 0, 0);
        S1 = __builtin_amdgcn_mfma_f32_32x32x16_bf16(qa, kb1, S1, 0, 0, 0);

        unsigned short* Pw = Ps[wv];
        #pragma unroll
        for (int r = 0; r < 16; ++r) {
            int qrow = (r&3) + 8*(r>>2) + 4*lhi;
            Pw[qrow*64 + l31]      = f2bf(exp2fast(S0[r]));
            Pw[qrow*64 + 32 + l31] = f2bf(exp2fast(S1[r]));
        }

        float lpart = 0.f;
        bf16x8 pa[4];
        #pragma unroll
        for (int kc = 0; kc < 4; ++kc) {
            pa[kc] = *(const bf16x8*)(Pw + l31*64 + kc*16 + 8*lhi);
            #pragma unroll
            for (int j = 0; j < 8; ++j)
                lpart += bf2f((unsigned short)pa[kc][j]);
        }
        lpart += __shfl_xor(lpart, 32, 64);
        lsum_reg += lpart;

        #pragma unroll
        for (int kc = 0; kc < 4; ++kc) {
            bf16x8 vb0 = *(const bf16x8*)(Vs + ((kc*2+0)*64 + lane)*8);
            bf16x8 vb1 = *(const bf16x8*)(Vs + ((kc*2+1)*64 + lane)*8);
            acc0 = __builtin_amdgcn_mfma_f32_32x32x16_bf16(pa[kc], vb0, acc0, 0, 0, 0);
            acc1 = __builtin_amdgcn_mfma_f32_32x32x16_bf16(pa[kc], vb1, acc1, 0, 0, 0);
        }
    }

    int qpix[16];
    #pragma unroll
    for (int r = 0; r < 16; ++r) {
        int qrow = (r&3) + 8*(r>>2) + 4*lhi;
        int p = q0 + wv*32 + qrow;
        int half = p & 1, pw = p >> 1;
        qpix[r] = (half<<12) + (((si<<hb)|(pw>>hb))<<6) + ((sj<<hb)|(pw&wlm));
    }
    float* Cst = CTXU + st*524288;
    #pragma unroll
    for (int r = 0; r < 16; ++r) {
        atomAdd(Cst + l31*8192      + qpix[r], acc0[r]);
        atomAdd(Cst + (32+l31)*8192 + qpix[r], acc1[r]);
    }
    if (lane < 32) {
        int p = q0 + wv*32 + l31;
        int half = p & 1, pw = p >> 1;
        int pixq = (half<<12) + (((si<<hb)|(pw>>hb))<<6) + ((sj<<hb)|(pw&wlm));
        atomAdd(LSUM + st*8192 + pixq, lsum_reg);
    }
}

// ---------------------------------------------------------------------------
// Kernel 3: normalize ctx by lsum + final 1x1 conv (256->64). 256 WGs.
// ---------------------------------------------------------------------------
__global__ __launch_bounds__(256) void normconv_kernel(
    const float* __restrict__ CTXU, const float* __restrict__ LSUM,
    const float* __restrict__ Wo, float* __restrict__ out)
{
    __shared__ float cs[256][33];
    __shared__ float linv[4][32];
    const int t = threadIdx.x;
    const int px0 = blockIdx.x * 32;

    if (t < 128) {
        int stt = t >> 5, i = t & 31;
        linv[stt][i] = 1.f / LSUM[stt*8192 + px0 + i];
    }
    __syncthreads();
    for (int idx = t; idx < 256*32; idx += 256) {
        int d = idx >> 5, i = idx & 31;
        int stt = d >> 6, cv = d & 63;
        cs[d][i] = CTXU[stt*524288 + cv*8192 + px0 + i] * linv[stt][i];
    }
    __syncthreads();

    const int i = t & 31;
    const int pix = px0 + i;
    const int half = pix >> 12, hw = pix & 4095;
    float* obase = out + half*262144 + hw;
    for (int oc = (t >> 5); oc < 64; oc += 8) {
        const float* wp = Wo + oc*256;
        float accv = 0.f;
        #pragma unroll 8
        for (int d = 0; d < 256; ++d) accv += wp[d]*cs[d][i];
        obase[oc*4096] = accv;
    }
}

// ---------------------------------------------------------------------------
extern "C" void kernel_launch(void* const* d_in, const int* in_sizes, int n_in,
                              void* d_out, int out_size, void* d_ws, size_t ws_size,
                              hipStream_t stream)
{
    (void)out_size; (void)ws_size;
    const float *x1, *x2, *Wq, *bq, *gq, *beq, *Wk, *bk, *gk, *bek, *Wv, *bv, *Wo;

    if (n_in >= 13 && in_sizes[0] == 2048) {       // sorted-key order (insurance)
        Wk  = (const float*)d_in[0];  Wo  = (const float*)d_in[1];
        Wq  = (const float*)d_in[2];  Wv  = (const float*)d_in[3];
        bek = (const float*)d_in[4];  beq = (const float*)d_in[5];
        bk  = (const float*)d_in[6];  bq  = (const float*)d_in[7];
        bv  = (const float*)d_in[8];  gk  = (const float*)d_in[9];
        gq  = (const float*)d_in[10];
        x1  = (const float*)d_in[11]; x2  = (const float*)d_in[12];
    } else {                                        // insertion order (proven)
        x1  = (const float*)d_in[0];  x2  = (const float*)d_in[1];
        Wq  = (const float*)d_in[2];  bq  = (const float*)d_in[3];
        gq  = (const float*)d_in[4];  beq = (const float*)d_in[5];
        Wk  = (const float*)d_in[6];  bk  = (const float*)d_in[7];
        gk  = (const float*)d_in[8];  bek = (const float*)d_in[9];
        Wv  = (const float*)d_in[10]; bv  = (const float*)d_in[11];
        Wo  = (const float*)d_in[12];
    }

    unsigned short* Qb = (unsigned short*)d_ws;     // 262144 ush
    unsigned short* Kb = Qb + 262144;               // 262144 ush
    unsigned short* Vf = Kb + 262144;               // 2097152 ush
    float* Cw = (float*)d_ws + 1310720;             // 2097152 fl
    float* Lw = Cw + 2097152;                       // 32768 fl

    zero_kernel<<<2080, 256, 0, stream>>>((float4*)Cw);
    proj_qk_kernel<<<64, 256, 0, stream>>>(x1,x2,Wq,bq,gq,beq,Wk,bk,gk,bek,Qb,Kb);
    proj_v_kernel<<<512, 256, 0, stream>>>(x1,x2,Wv,bv,Vf);
    attn_kernel<<<960, 256, 0, stream>>>(Qb,Kb,Vf,Cw,Lw);
    normconv_kernel<<<256, 256, 0, stream>>>(Cw, Lw, Wo, (float*)d_out);
}

// Round 11
// 349.063 us; speedup vs baseline: 1.7072x; 1.3444x over previous
//
#include <hip/hip_runtime.h>

// ---------------------------------------------------------------------------
// StaNet PAM — round 11: atomic-free attention (partial slabs + reduction).
// Inputs fp32 insertion-order (proven), output fp32 (proven).
// Key-splits (2,2,1,1) write disjoint fp32 partial-ctx slabs; normconv sums
// slabs, normalizes by summed lsum, applies the final 1x1 conv.
//
// Workspace (float offsets), total 18.02 MB (< 18.87 MB proven in r2/r3):
//   Qb   @ ush 0       : 262144 ush  [st][gp][ch] bf16 (Q pre-scaled QMUL)
//   Kb   @ ush 262144  : 262144 ush  [st][gp][ch] bf16
//   Vf   @ ush 524288  : 2097152 ush [st][blk][ch][p] bf16
//   PART @ fl  1310720 : 6*524288 fl [slot][tile][qrow32][ch64]
//   LPART@ fl  4456448 : 6*8192 fl   [slot][gp]
// slots: 0,1 = st0 splits; 2,3 = st1 splits; 4 = st2; 5 = st3.
// gp = blk*P + p (stage-local point); tile = gp>>5; qrow = gp&31.
// pix = half*4096 + h*64 + w; p = (((hi<<hb)|wi)<<1)|half.
// MFMA 32x32x16 bf16: A[m][k] m=lane&31,k=8*(lane>>5)+j; B[k][n] n=lane&31;
// C/D col=lane&31, row=(reg&3)+8*(reg>>2)+4*(lane>>5).
// ---------------------------------------------------------------------------

typedef short bf16x8 __attribute__((ext_vector_type(8)));
typedef float f32x16 __attribute__((ext_vector_type(16)));

__device__ __forceinline__ float bf2f(unsigned short u){ union{unsigned int i;float f;}v; v.i=((unsigned int)u)<<16; return v.f; }
__device__ __forceinline__ unsigned short f2bf(float f){
    union{float f;unsigned int i;}v; v.f=f;
    unsigned int r = v.i + 0x7fffu + ((v.i>>16)&1u);
    return (unsigned short)(r>>16);
}
__device__ __forceinline__ float exp2fast(float x){ return __builtin_amdgcn_exp2f(x); }

#define QMUL 0.5100697233f   // 8^-0.5 * log2(e), folded into Q

// ---------------------------------------------------------------------------
// Kernel 1a: Q+K projections. 256 WGs (4 st x 64 chunks of 128 gp).
// x-tile transposed in LDS [g][68]; per-thread x row in VGPRs (b128 reads).
// ---------------------------------------------------------------------------
__global__ __launch_bounds__(256) void proj_qk_kernel(
    const float* __restrict__ x1, const float* __restrict__ x2,
    const float* __restrict__ Wq, const float* __restrict__ bq,
    const float* __restrict__ gq, const float* __restrict__ beq,
    const float* __restrict__ Wk, const float* __restrict__ bk,
    const float* __restrict__ gk, const float* __restrict__ bek,
    unsigned short* __restrict__ Qb, unsigned short* __restrict__ Kb)
{
    __shared__ __align__(16) float xs[128][68];
    const int wg = blockIdx.x, st = wg >> 6, chunk = wg & 63;
    const int lgP = 13 - 2*st, Pm1 = (1<<lgP) - 1;
    const int hb = 6 - st, wlm = (1<<hb) - 1;
    const int t = threadIdx.x;
    const int gp0 = chunk*128;
    const int blk = gp0 >> lgP, p0 = gp0 & Pm1;
    const int si = blk >> st, sj = blk & ((1<<st)-1);
    const int hwbase = ((si<<hb)<<6) | (sj<<hb);

    for (int idx = t; idx < 8192; idx += 256) {
        int c = idx >> 7, g = idx & 127;
        int p = p0 + g, half = p & 1, pw = p >> 1;
        int hw = hwbase | ((pw>>hb)<<6) | (pw & wlm);
        xs[g][c] = (half ? x2 : x1)[c*4096 + hw];
    }
    __syncthreads();

    const int g = t & 127, qk = t >> 7;          // wave-uniform qk
    const int gp = gp0 + g;
    float xr[64];
    #pragma unroll
    for (int q4 = 0; q4 < 16; ++q4)
        *(float4*)&xr[q4*4] = *(const float4*)&xs[g][q4*4];

    const float* Wb  = qk ? Wk  : Wq;
    const float* bb  = qk ? bk  : bq;
    const float* gb  = qk ? gk  : gq;
    const float* beb = qk ? bek : beq;
    unsigned short outv[8];
    for (int ch = 0; ch < 8; ++ch) {
        const float* wp = Wb + (st*8 + ch)*64;
        float d = 0.f;
        #pragma unroll
        for (int k = 0; k < 64; ++k) d += wp[k]*xr[k];
        float gm = gb[st*8+ch];
        float val = gm*(d + bb[st*8+ch]) + beb[st*8+ch];
        if (!qk) val *= QMUL;
        outv[ch] = f2bf(val);
    }
    unsigned short* dst = (qk ? Kb : Qb) + st*65536 + gp*8;
    *(uint4*)dst = *(uint4*)outv;
}

// ---------------------------------------------------------------------------
// Kernel 1b: V projection. 512 WGs (4 st x 64 ch x 2 half-ranges).
// ---------------------------------------------------------------------------
__global__ __launch_bounds__(256) void proj_v_kernel(
    const float* __restrict__ x1, const float* __restrict__ x2,
    const float* __restrict__ Wv, const float* __restrict__ bv,
    unsigned short* __restrict__ Vf)
{
    const int wg = blockIdx.x;
    const int st = wg >> 7, r = wg & 127, ch = r >> 1, pc = r & 1;
    const int lgP = 13 - 2*st, Pm1 = (1<<lgP) - 1;
    const int hb = 6 - st, wlm = (1<<hb) - 1;
    const int t = threadIdx.x;

    float wr[64];
    #pragma unroll
    for (int k = 0; k < 64; ++k) wr[k] = Wv[(st*64 + ch)*64 + k];
    const float bias = bv[st*64 + ch];

    unsigned short* Vst = Vf + st*524288;
    for (int it = 0; it < 16; ++it) {
        int gp = pc*4096 + it*256 + t;
        int blk = gp >> lgP, p = gp & Pm1;
        int si = blk >> st, sj = blk & ((1<<st)-1);
        int half = p & 1, pw = p >> 1;
        int hw = ((((si<<hb)|(pw>>hb))<<6)) | ((sj<<hb)|(pw&wlm));
        const float* src = half ? x2 : x1;
        float acc = bias;
        #pragma unroll
        for (int k = 0; k < 64; ++k) acc += wr[k]*src[k*4096 + hw];
        Vst[(blk << (lgP+6)) + (ch << lgP) + p] = f2bf(acc);
    }
}

// ---------------------------------------------------------------------------
// Kernel 2: MFMA flash attention, atomic-free. 384 WGs x 256 threads.
//   wg<128 : st0: q0=(wg>>1)*128, split=wg&1, kbase=split*4096, nk=4096
//   wg<256 : st1: r=wg-128: blk=r>>5, r2=r&31, q0=(r2>>1)*128, split=r2&1,
//            kbase=split*1024, nk=1024
//   wg<320 : st2: r=wg-256: blk=r>>2, q0=(r&3)*128, nk=512
//   else   : st3: blk=wg-320, q0=0, nk=128
// Each wave owns a 32-query tile; writes its partial ctx slab coalesced.
// ---------------------------------------------------------------------------
__global__ __launch_bounds__(256) void attn_kernel(
    const unsigned short* __restrict__ Qb, const unsigned short* __restrict__ Kb,
    const unsigned short* __restrict__ Vf,
    float* __restrict__ PART, float* __restrict__ LPART)
{
    __shared__ __align__(16) unsigned short Ks[512];        // [key64][ch8]
    __shared__ __align__(16) unsigned short Vs[4096];       // frag-order 8KB
    __shared__ __align__(16) unsigned short Ps[4][2304];    // [q32][72] per wave

    const int wg = blockIdx.x;
    int st, blk, q0, kbase, nk, slot;
    if (wg < 128)      { st=0; blk=0; q0=(wg>>1)*128; slot=wg&1;
                         kbase=(wg&1)*4096; nk=4096; }
    else if (wg < 256) { int r=wg-128; st=1; blk=r>>5; int r2=r&31;
                         q0=(r2>>1)*128; slot=2+(r2&1); kbase=(r2&1)*1024; nk=1024; }
    else if (wg < 320) { int r=wg-256; st=2; blk=r>>2; q0=(r&3)*128;
                         slot=4; kbase=0; nk=512; }
    else               { st=3; blk=wg-320; q0=0; slot=5; kbase=0; nk=128; }

    const int P = 8192 >> (2*st);
    const int t = threadIdx.x, lane = t & 63, wv = t >> 6;
    const int l31 = lane & 31, lhi = lane >> 5;

    const unsigned short* Qg = Qb + st*65536 + blk*P*8;
    const unsigned short* Kg = Kb + st*65536 + blk*P*8;
    const unsigned short* Vg = Vf + st*524288 + blk*P*64;   // [ch][p]

    bf16x8 qa;
    #pragma unroll
    for (int j = 0; j < 8; ++j) qa[j] = 0;
    if (lane < 32) qa = *(const bf16x8*)(Qg + (q0 + wv*32 + l31)*8);

    f32x16 acc0, acc1;
    #pragma unroll
    for (int r = 0; r < 16; ++r) { acc0[r] = 0.f; acc1[r] = 0.f; }
    float lsum_reg = 0.f;

    for (int k0 = kbase; k0 < kbase + nk; k0 += 64) {
        __syncthreads();
        if (t < 64) ((uint4*)Ks)[t] = ((const uint4*)(Kg + k0*8))[t];
        #pragma unroll
        for (int r = 0; r < 2; ++r) {           // V fragment swizzle, 16B/16B
            int task = t + r*256;
            int ch = task >> 3, o = task & 7;
            uint4 v = *(const uint4*)(Vg + ch*P + k0 + o*8);
            *(uint4*)(Vs + (o>>1)*1024 + (ch>>5)*512 + ((((o&1)<<5) | (ch&31)))*8) = v;
        }
        __syncthreads();

        bf16x8 kb0 = *(const bf16x8*)(Ks + l31*8);
        bf16x8 kb1 = *(const bf16x8*)(Ks + (32 + l31)*8);
        f32x16 S0, S1;
        #pragma unroll
        for (int r = 0; r < 16; ++r) { S0[r] = 0.f; S1[r] = 0.f; }
        S0 = __builtin_amdgcn_mfma_f32_32x32x16_bf16(qa, kb0, S0, 0, 0, 0);
        S1 = __builtin_amdgcn_mfma_f32_32x32x16_bf16(qa, kb1, S1, 0, 0, 0);

        unsigned short* Pw = Ps[wv];
        #pragma unroll
        for (int r = 0; r < 16; ++r) {
            int qrow = (r&3) + 8*(r>>2) + 4*lhi;
            Pw[qrow*72 + l31]      = f2bf(exp2fast(S0[r]));
            Pw[qrow*72 + 32 + l31] = f2bf(exp2fast(S1[r]));
        }

        float lpart = 0.f;
        bf16x8 pa[4];
        #pragma unroll
        for (int kc = 0; kc < 4; ++kc) {
            pa[kc] = *(const bf16x8*)(Pw + l31*72 + kc*16 + 8*lhi);
            #pragma unroll
            for (int j = 0; j < 8; ++j)
                lpart += bf2f((unsigned short)pa[kc][j]);
        }
        lpart += __shfl_xor(lpart, 32, 64);
        lsum_reg += lpart;

        #pragma unroll
        for (int kc = 0; kc < 4; ++kc) {
            bf16x8 vb0 = *(const bf16x8*)(Vs + ((kc*2+0)*64 + lane)*8);
            bf16x8 vb1 = *(const bf16x8*)(Vs + ((kc*2+1)*64 + lane)*8);
            acc0 = __builtin_amdgcn_mfma_f32_32x32x16_bf16(pa[kc], vb0, acc0, 0, 0, 0);
            acc1 = __builtin_amdgcn_mfma_f32_32x32x16_bf16(pa[kc], vb1, acc1, 0, 0, 0);
        }
    }

    // epilogue: coalesced partial stores (no atomics)
    const int tile = ((blk*P + q0) >> 5) + wv;
    float* Pslab = PART + slot*524288 + tile*2048;
    #pragma unroll
    for (int r = 0; r < 16; ++r) {
        int qrow = (r&3) + 8*(r>>2) + 4*lhi;
        Pslab[qrow*64 + l31]      = acc0[r];
        Pslab[qrow*64 + 32 + l31] = acc1[r];
    }
    if (lane < 32)
        LPART[slot*8192 + tile*32 + l31] = lsum_reg;
}

// ---------------------------------------------------------------------------
// Kernel 3: sum partial slabs, normalize, final 1x1 conv (256->64). 256 WGs.
// ---------------------------------------------------------------------------
__global__ __launch_bounds__(256) void normconv_kernel(
    const float* __restrict__ PART, const float* __restrict__ LPART,
    const float* __restrict__ Wo, float* __restrict__ out)
{
    __shared__ float cs[256][33];
    __shared__ float linv[4][32];
    __shared__ int gpar[4][32];
    const int t = threadIdx.x;
    const int px0 = blockIdx.x * 32;

    if (t < 128) {
        const int s0tab[4] = {0,2,4,5};
        const int sctab[4] = {2,2,1,1};
        int stt = t >> 5, i = t & 31;
        int pix = px0 + i;
        int half = pix >> 12, hw = pix & 4095;
        int h = hw >> 6, w = hw & 63;
        int hb = 6 - stt, wlm = (1<<hb)-1;
        int si = h >> hb, sj = w >> hb, hi = h & wlm, wi = w & wlm;
        int blk = (si << stt) | sj;
        int p = (((hi << hb) | wi) << 1) | half;
        int gp = blk*(8192>>(2*stt)) + p;
        gpar[stt][i] = gp;
        int s0 = s0tab[stt];
        float l = LPART[s0*8192 + gp];
        if (sctab[stt] == 2) l += LPART[(s0+1)*8192 + gp];
        linv[stt][i] = 1.f / l;
    }
    __syncthreads();

    for (int idx = t; idx < 256*32; idx += 256) {
        const int s0tab[4] = {0,2,4,5};
        const int sctab[4] = {2,2,1,1};
        int d = idx >> 5, i = idx & 31;        // d = st*64 + cv
        int stt = d >> 6, cv = d & 63;
        int gp = gpar[stt][i];
        int addr = (gp>>5)*2048 + (gp&31)*64 + cv;
        int s0 = s0tab[stt];
        float v = PART[s0*524288 + addr];
        if (sctab[stt] == 2) v += PART[(s0+1)*524288 + addr];
        cs[d][i] = v * linv[stt][i];
    }
    __syncthreads();

    const int i = t & 31;
    const int pix = px0 + i;
    const int half = pix >> 12, hw = pix & 4095;
    float* obase = out + half*262144 + hw;
    for (int oc = (t >> 5); oc < 64; oc += 8) {
        const float* wp = Wo + oc*256;
        float accv = 0.f;
        #pragma unroll 8
        for (int d = 0; d < 256; ++d) accv += wp[d]*cs[d][i];
        obase[oc*4096] = accv;
    }
}

// ---------------------------------------------------------------------------
extern "C" void kernel_launch(void* const* d_in, const int* in_sizes, int n_in,
                              void* d_out, int out_size, void* d_ws, size_t ws_size,
                              hipStream_t stream)
{
    (void)out_size; (void)ws_size;
    const float *x1, *x2, *Wq, *bq, *gq, *beq, *Wk, *bk, *gk, *bek, *Wv, *bv, *Wo;

    if (n_in >= 13 && in_sizes[0] == 2048) {       // sorted-key order (insurance)
        Wk  = (const float*)d_in[0];  Wo  = (const float*)d_in[1];
        Wq  = (const float*)d_in[2];  Wv  = (const float*)d_in[3];
        bek = (const float*)d_in[4];  beq = (const float*)d_in[5];
        bk  = (const float*)d_in[6];  bq  = (const float*)d_in[7];
        bv  = (const float*)d_in[8];  gk  = (const float*)d_in[9];
        gq  = (const float*)d_in[10];
        x1  = (const float*)d_in[11]; x2  = (const float*)d_in[12];
    } else {                                        // insertion order (proven)
        x1  = (const float*)d_in[0];  x2  = (const float*)d_in[1];
        Wq  = (const float*)d_in[2];  bq  = (const float*)d_in[3];
        gq  = (const float*)d_in[4];  beq = (const float*)d_in[5];
        Wk  = (const float*)d_in[6];  bk  = (const float*)d_in[7];
        gk  = (const float*)d_in[8];  bek = (const float*)d_in[9];
        Wv  = (const float*)d_in[10]; bv  = (const float*)d_in[11];
        Wo  = (const float*)d_in[12];
    }

    unsigned short* Qb = (unsigned short*)d_ws;     // 262144 ush
    unsigned short* Kb = Qb + 262144;               // 262144 ush
    unsigned short* Vf = Kb + 262144;               // 2097152 ush
    float* PART  = (float*)d_ws + 1310720;          // 3145728 fl
    float* LPART = PART + 3145728;                  // 49152 fl

    proj_qk_kernel<<<256, 256, 0, stream>>>(x1,x2,Wq,bq,gq,beq,Wk,bk,gk,bek,Qb,Kb);
    proj_v_kernel<<<512, 256, 0, stream>>>(x1,x2,Wv,bv,Vf);
    attn_kernel<<<384, 256, 0, stream>>>(Qb,Kb,Vf,PART,LPART);
    normconv_kernel<<<256, 256, 0, stream>>>(PART, LPART, Wo, (float*)d_out);
}

// Round 12
// 271.829 us; speedup vs baseline: 2.1922x; 1.2841x over previous
//
#include <hip/hip_runtime.h>

// ---------------------------------------------------------------------------
// StaNet PAM — round 12: r11 + proj_v rewrite (kill latency-serialized loads).
// Everything except proj_v_kernel is byte-identical to r11 (passed, 6.1e-5).
//
// Workspace (float offsets), total 18.02 MB:
//   Qb   @ ush 0       : 262144 ush  [st][gp][ch] bf16 (Q pre-scaled QMUL)
//   Kb   @ ush 262144  : 262144 ush  [st][gp][ch] bf16
//   Vf   @ ush 524288  : 2097152 ush [st][blk][ch][p] bf16
//   PART @ fl  1310720 : 6*524288 fl [slot][tile][qrow32][ch64]
//   LPART@ fl  4456448 : 6*8192 fl   [slot][gp]
// slots: 0,1 = st0 splits; 2,3 = st1 splits; 4 = st2; 5 = st3.
// gp = blk*P + p; pix = half*4096 + h*64 + w; p = (((hi<<hb)|wi)<<1)|half.
// MFMA 32x32x16 bf16: A[m][k] m=lane&31,k=8*(lane>>5)+j; B[k][n] n=lane&31;
// C/D col=lane&31, row=(reg&3)+8*(reg>>2)+4*(lane>>5).
// ---------------------------------------------------------------------------

typedef short bf16x8 __attribute__((ext_vector_type(8)));
typedef float f32x16 __attribute__((ext_vector_type(16)));

__device__ __forceinline__ float bf2f(unsigned short u){ union{unsigned int i;float f;}v; v.i=((unsigned int)u)<<16; return v.f; }
__device__ __forceinline__ unsigned short f2bf(float f){
    union{float f;unsigned int i;}v; v.f=f;
    unsigned int r = v.i + 0x7fffu + ((v.i>>16)&1u);
    return (unsigned short)(r>>16);
}
__device__ __forceinline__ float exp2fast(float x){ return __builtin_amdgcn_exp2f(x); }

#define QMUL 0.5100697233f   // 8^-0.5 * log2(e), folded into Q

// ---------------------------------------------------------------------------
// Kernel 1a: Q+K projections. 256 WGs (4 st x 64 chunks of 128 gp). (r11)
// ---------------------------------------------------------------------------
__global__ __launch_bounds__(256) void proj_qk_kernel(
    const float* __restrict__ x1, const float* __restrict__ x2,
    const float* __restrict__ Wq, const float* __restrict__ bq,
    const float* __restrict__ gq, const float* __restrict__ beq,
    const float* __restrict__ Wk, const float* __restrict__ bk,
    const float* __restrict__ gk, const float* __restrict__ bek,
    unsigned short* __restrict__ Qb, unsigned short* __restrict__ Kb)
{
    __shared__ __align__(16) float xs[128][68];
    const int wg = blockIdx.x, st = wg >> 6, chunk = wg & 63;
    const int lgP = 13 - 2*st, Pm1 = (1<<lgP) - 1;
    const int hb = 6 - st, wlm = (1<<hb) - 1;
    const int t = threadIdx.x;
    const int gp0 = chunk*128;
    const int blk = gp0 >> lgP, p0 = gp0 & Pm1;
    const int si = blk >> st, sj = blk & ((1<<st)-1);
    const int hwbase = ((si<<hb)<<6) | (sj<<hb);

    for (int idx = t; idx < 8192; idx += 256) {
        int c = idx >> 7, g = idx & 127;
        int p = p0 + g, half = p & 1, pw = p >> 1;
        int hw = hwbase | ((pw>>hb)<<6) | (pw & wlm);
        xs[g][c] = (half ? x2 : x1)[c*4096 + hw];
    }
    __syncthreads();

    const int g = t & 127, qk = t >> 7;          // wave-uniform qk
    const int gp = gp0 + g;
    float xr[64];
    #pragma unroll
    for (int q4 = 0; q4 < 16; ++q4)
        *(float4*)&xr[q4*4] = *(const float4*)&xs[g][q4*4];

    const float* Wb  = qk ? Wk  : Wq;
    const float* bb  = qk ? bk  : bq;
    const float* gb  = qk ? gk  : gq;
    const float* beb = qk ? bek : beq;
    unsigned short outv[8];
    for (int ch = 0; ch < 8; ++ch) {
        const float* wp = Wb + (st*8 + ch)*64;
        float d = 0.f;
        #pragma unroll
        for (int k = 0; k < 64; ++k) d += wp[k]*xr[k];
        float gm = gb[st*8+ch];
        float val = gm*(d + bb[st*8+ch]) + beb[st*8+ch];
        if (!qk) val *= QMUL;
        outv[ch] = f2bf(val);
    }
    unsigned short* dst = (qk ? Kb : Qb) + st*65536 + gp*8;
    *(uint4*)dst = *(uint4*)outv;
}

// ---------------------------------------------------------------------------
// Kernel 1b: V projection, tiled (NEW). 256 WGs (4 st x 64 chunks of 128 gp).
// x-tile in LDS once; thread = (point, ch-half): 32 ch x 64 FMA from VGPR
// x-row; results through LDS out-tile -> coalesced uint4 stores to [ch][p].
// ---------------------------------------------------------------------------
__global__ __launch_bounds__(256) void proj_v_kernel(
    const float* __restrict__ x1, const float* __restrict__ x2,
    const float* __restrict__ Wv, const float* __restrict__ bv,
    unsigned short* __restrict__ Vf)
{
    __shared__ __align__(16) float xs[128][68];
    __shared__ __align__(16) unsigned short vout[64][128];
    const int wg = blockIdx.x, st = wg >> 6, chunk = wg & 63;
    const int lgP = 13 - 2*st, Pm1 = (1<<lgP) - 1;
    const int hb = 6 - st, wlm = (1<<hb) - 1;
    const int t = threadIdx.x;
    const int gp0 = chunk*128;
    const int blk = gp0 >> lgP, p0 = gp0 & Pm1;
    const int si = blk >> st, sj = blk & ((1<<st)-1);
    const int hwbase = ((si<<hb)<<6) | (sj<<hb);

    for (int idx = t; idx < 8192; idx += 256) {
        int c = idx >> 7, g = idx & 127;
        int p = p0 + g, half = p & 1, pw = p >> 1;
        int hw = hwbase | ((pw>>hb)<<6) | (pw & wlm);
        xs[g][c] = (half ? x2 : x1)[c*4096 + hw];
    }
    __syncthreads();

    const int g = t & 127, chh = (t >> 7) * 32;   // wave-uniform ch-half
    float xr[64];
    #pragma unroll
    for (int q4 = 0; q4 < 16; ++q4)
        *(float4*)&xr[q4*4] = *(const float4*)&xs[g][q4*4];

    for (int cc = 0; cc < 32; ++cc) {
        int ch = chh + cc;
        const float* wp = Wv + (st*64 + ch)*64;
        float d = bv[st*64 + ch];
        #pragma unroll
        for (int k = 0; k < 64; ++k) d += wp[k]*xr[k];
        vout[ch][g] = f2bf(d);
    }
    __syncthreads();

    unsigned short* Vst = Vf + st*524288 + (blk << (lgP+6));
    #pragma unroll
    for (int r = 0; r < 4; ++r) {
        int tt = t + r*256;
        int ch = tt >> 4, o = tt & 15;
        *(uint4*)(Vst + (ch << lgP) + p0 + o*8) = *(const uint4*)&vout[ch][o*8];
    }
}

// ---------------------------------------------------------------------------
// Kernel 2: MFMA flash attention, atomic-free. 384 WGs x 256 threads. (r11)
// ---------------------------------------------------------------------------
__global__ __launch_bounds__(256) void attn_kernel(
    const unsigned short* __restrict__ Qb, const unsigned short* __restrict__ Kb,
    const unsigned short* __restrict__ Vf,
    float* __restrict__ PART, float* __restrict__ LPART)
{
    __shared__ __align__(16) unsigned short Ks[512];        // [key64][ch8]
    __shared__ __align__(16) unsigned short Vs[4096];       // frag-order 8KB
    __shared__ __align__(16) unsigned short Ps[4][2304];    // [q32][72] per wave

    const int wg = blockIdx.x;
    int st, blk, q0, kbase, nk, slot;
    if (wg < 128)      { st=0; blk=0; q0=(wg>>1)*128; slot=wg&1;
                         kbase=(wg&1)*4096; nk=4096; }
    else if (wg < 256) { int r=wg-128; st=1; blk=r>>5; int r2=r&31;
                         q0=(r2>>1)*128; slot=2+(r2&1); kbase=(r2&1)*1024; nk=1024; }
    else if (wg < 320) { int r=wg-256; st=2; blk=r>>2; q0=(r&3)*128;
                         slot=4; kbase=0; nk=512; }
    else               { st=3; blk=wg-320; q0=0; slot=5; kbase=0; nk=128; }

    const int P = 8192 >> (2*st);
    const int t = threadIdx.x, lane = t & 63, wv = t >> 6;
    const int l31 = lane & 31, lhi = lane >> 5;

    const unsigned short* Qg = Qb + st*65536 + blk*P*8;
    const unsigned short* Kg = Kb + st*65536 + blk*P*8;
    const unsigned short* Vg = Vf + st*524288 + blk*P*64;   // [ch][p]

    bf16x8 qa;
    #pragma unroll
    for (int j = 0; j < 8; ++j) qa[j] = 0;
    if (lane < 32) qa = *(const bf16x8*)(Qg + (q0 + wv*32 + l31)*8);

    f32x16 acc0, acc1;
    #pragma unroll
    for (int r = 0; r < 16; ++r) { acc0[r] = 0.f; acc1[r] = 0.f; }
    float lsum_reg = 0.f;

    for (int k0 = kbase; k0 < kbase + nk; k0 += 64) {
        __syncthreads();
        if (t < 64) ((uint4*)Ks)[t] = ((const uint4*)(Kg + k0*8))[t];
        #pragma unroll
        for (int r = 0; r < 2; ++r) {           // V fragment swizzle, 16B/16B
            int task = t + r*256;
            int ch = task >> 3, o = task & 7;
            uint4 v = *(const uint4*)(Vg + ch*P + k0 + o*8);
            *(uint4*)(Vs + (o>>1)*1024 + (ch>>5)*512 + ((((o&1)<<5) | (ch&31)))*8) = v;
        }
        __syncthreads();

        bf16x8 kb0 = *(const bf16x8*)(Ks + l31*8);
        bf16x8 kb1 = *(const bf16x8*)(Ks + (32 + l31)*8);
        f32x16 S0, S1;
        #pragma unroll
        for (int r = 0; r < 16; ++r) { S0[r] = 0.f; S1[r] = 0.f; }
        S0 = __builtin_amdgcn_mfma_f32_32x32x16_bf16(qa, kb0, S0, 0, 0, 0);
        S1 = __builtin_amdgcn_mfma_f32_32x32x16_bf16(qa, kb1, S1, 0, 0, 0);

        unsigned short* Pw = Ps[wv];
        #pragma unroll
        for (int r = 0; r < 16; ++r) {
            int qrow = (r&3) + 8*(r>>2) + 4*lhi;
            Pw[qrow*72 + l31]      = f2bf(exp2fast(S0[r]));
            Pw[qrow*72 + 32 + l31] = f2bf(exp2fast(S1[r]));
        }

        float lpart = 0.f;
        bf16x8 pa[4];
        #pragma unroll
        for (int kc = 0; kc < 4; ++kc) {
            pa[kc] = *(const bf16x8*)(Pw + l31*72 + kc*16 + 8*lhi);
            #pragma unroll
            for (int j = 0; j < 8; ++j)
                lpart += bf2f((unsigned short)pa[kc][j]);
        }
        lpart += __shfl_xor(lpart, 32, 64);
        lsum_reg += lpart;

        #pragma unroll
        for (int kc = 0; kc < 4; ++kc) {
            bf16x8 vb0 = *(const bf16x8*)(Vs + ((kc*2+0)*64 + lane)*8);
            bf16x8 vb1 = *(const bf16x8*)(Vs + ((kc*2+1)*64 + lane)*8);
            acc0 = __builtin_amdgcn_mfma_f32_32x32x16_bf16(pa[kc], vb0, acc0, 0, 0, 0);
            acc1 = __builtin_amdgcn_mfma_f32_32x32x16_bf16(pa[kc], vb1, acc1, 0, 0, 0);
        }
    }

    // epilogue: coalesced partial stores (no atomics)
    const int tile = ((blk*P + q0) >> 5) + wv;
    float* Pslab = PART + slot*524288 + tile*2048;
    #pragma unroll
    for (int r = 0; r < 16; ++r) {
        int qrow = (r&3) + 8*(r>>2) + 4*lhi;
        Pslab[qrow*64 + l31]      = acc0[r];
        Pslab[qrow*64 + 32 + l31] = acc1[r];
    }
    if (lane < 32)
        LPART[slot*8192 + tile*32 + l31] = lsum_reg;
}

// ---------------------------------------------------------------------------
// Kernel 3: sum partial slabs, normalize, final 1x1 conv (256->64). (r11)
// ---------------------------------------------------------------------------
__global__ __launch_bounds__(256) void normconv_kernel(
    const float* __restrict__ PART, const float* __restrict__ LPART,
    const float* __restrict__ Wo, float* __restrict__ out)
{
    __shared__ float cs[256][33];
    __shared__ float linv[4][32];
    __shared__ int gpar[4][32];
    const int t = threadIdx.x;
    const int px0 = blockIdx.x * 32;

    if (t < 128) {
        const int s0tab[4] = {0,2,4,5};
        const int sctab[4] = {2,2,1,1};
        int stt = t >> 5, i = t & 31;
        int pix = px0 + i;
        int half = pix >> 12, hw = pix & 4095;
        int h = hw >> 6, w = hw & 63;
        int hb = 6 - stt, wlm = (1<<hb)-1;
        int si = h >> hb, sj = w >> hb, hi = h & wlm, wi = w & wlm;
        int blk = (si << stt) | sj;
        int p = (((hi << hb) | wi) << 1) | half;
        int gp = blk*(8192>>(2*stt)) + p;
        gpar[stt][i] = gp;
        int s0 = s0tab[stt];
        float l = LPART[s0*8192 + gp];
        if (sctab[stt] == 2) l += LPART[(s0+1)*8192 + gp];
        linv[stt][i] = 1.f / l;
    }
    __syncthreads();

    for (int idx = t; idx < 256*32; idx += 256) {
        const int s0tab[4] = {0,2,4,5};
        const int sctab[4] = {2,2,1,1};
        int d = idx >> 5, i = idx & 31;        // d = st*64 + cv
        int stt = d >> 6, cv = d & 63;
        int gp = gpar[stt][i];
        int addr = (gp>>5)*2048 + (gp&31)*64 + cv;
        int s0 = s0tab[stt];
        float v = PART[s0*524288 + addr];
        if (sctab[stt] == 2) v += PART[(s0+1)*524288 + addr];
        cs[d][i] = v * linv[stt][i];
    }
    __syncthreads();

    const int i = t & 31;
    const int pix = px0 + i;
    const int half = pix >> 12, hw = pix & 4095;
    float* obase = out + half*262144 + hw;
    for (int oc = (t >> 5); oc < 64; oc += 8) {
        const float* wp = Wo + oc*256;
        float accv = 0.f;
        #pragma unroll 8
        for (int d = 0; d < 256; ++d) accv += wp[d]*cs[d][i];
        obase[oc*4096] = accv;
    }
}

// ---------------------------------------------------------------------------
extern "C" void kernel_launch(void* const* d_in, const int* in_sizes, int n_in,
                              void* d_out, int out_size, void* d_ws, size_t ws_size,
                              hipStream_t stream)
{
    (void)out_size; (void)ws_size;
    const float *x1, *x2, *Wq, *bq, *gq, *beq, *Wk, *bk, *gk, *bek, *Wv, *bv, *Wo;

    if (n_in >= 13 && in_sizes[0] == 2048) {       // sorted-key order (insurance)
        Wk  = (const float*)d_in[0];  Wo  = (const float*)d_in[1];
        Wq  = (const float*)d_in[2];  Wv  = (const float*)d_in[3];
        bek = (const float*)d_in[4];  beq = (const float*)d_in[5];
        bk  = (const float*)d_in[6];  bq  = (const float*)d_in[7];
        bv  = (const float*)d_in[8];  gk  = (const float*)d_in[9];
        gq  = (const float*)d_in[10];
        x1  = (const float*)d_in[11]; x2  = (const float*)d_in[12];
    } else {                                        // insertion order (proven)
        x1  = (const float*)d_in[0];  x2  = (const float*)d_in[1];
        Wq  = (const float*)d_in[2];  bq  = (const float*)d_in[3];
        gq  = (const float*)d_in[4];  beq = (const float*)d_in[5];
        Wk  = (const float*)d_in[6];  bk  = (const float*)d_in[7];
        gk  = (const float*)d_in[8];  bek = (const float*)d_in[9];
        Wv  = (const float*)d_in[10]; bv  = (const float*)d_in[11];
        Wo  = (const float*)d_in[12];
    }

    unsigned short* Qb = (unsigned short*)d_ws;     // 262144 ush
    unsigned short* Kb = Qb + 262144;               // 262144 ush
    unsigned short* Vf = Kb + 262144;               // 2097152 ush
    float* PART  = (float*)d_ws + 1310720;          // 3145728 fl
    float* LPART = PART + 3145728;                  // 49152 fl

    proj_qk_kernel<<<256, 256, 0, stream>>>(x1,x2,Wq,bq,gq,beq,Wk,bk,gk,bek,Qb,Kb);
    proj_v_kernel<<<256, 256, 0, stream>>>(x1,x2,Wv,bv,Vf);
    attn_kernel<<<384, 256, 0, stream>>>(Qb,Kb,Vf,PART,LPART);
    normconv_kernel<<<256, 256, 0, stream>>>(PART, LPART, Wo, (float*)d_out);
}

// Round 13
// 215.086 us; speedup vs baseline: 2.7705x; 1.2638x over previous
//
#include <hip/hip_runtime.h>

// ---------------------------------------------------------------------------
// StaNet PAM — round 13: barrier-free MFMA attention + intra-WG 4x key split.
// B-fragments (K and V) loaded DIRECTLY from global (no LDS staging, no
// K-loop barriers); P transpose stays per-wave LDS. 4 waves per WG share one
// 32-query tile, each covering nk/4 keys of the slot; partials merged via an
// LDS tree (3 barriers/WG). Slot structure identical to r11/r12, so
// proj_qk / proj_v / normconv are byte-identical to r12 (passed, 6.1e-5).
//
// Workspace (float offsets), total 18.02 MB:
//   Qb   @ ush 0       : 262144 ush  [st][gp][ch] bf16 (Q pre-scaled QMUL)
//   Kb   @ ush 262144  : 262144 ush  [st][gp][ch] bf16
//   Vf   @ ush 524288  : 2097152 ush [st][blk][ch][p] bf16
//   PART @ fl  1310720 : 6*524288 fl [slot][tile][qrow32][ch64]
//   LPART@ fl  4456448 : 6*8192 fl   [slot][gp]
// slots: 0,1 = st0 splits; 2,3 = st1 splits; 4 = st2; 5 = st3. tile == qt.
// MFMA 32x32x16 bf16: A[m][k] m=lane&31,k=8*(lane>>5)+j; B[k][n] n=lane&31;
// C/D col=lane&31, row=(reg&3)+8*(reg>>2)+4*(lane>>5).
// ---------------------------------------------------------------------------

typedef short bf16x8 __attribute__((ext_vector_type(8)));
typedef float f32x16 __attribute__((ext_vector_type(16)));

__device__ __forceinline__ float bf2f(unsigned short u){ union{unsigned int i;float f;}v; v.i=((unsigned int)u)<<16; return v.f; }
__device__ __forceinline__ unsigned short f2bf(float f){
    union{float f;unsigned int i;}v; v.f=f;
    unsigned int r = v.i + 0x7fffu + ((v.i>>16)&1u);
    return (unsigned short)(r>>16);
}
__device__ __forceinline__ float exp2fast(float x){ return __builtin_amdgcn_exp2f(x); }

#define QMUL 0.5100697233f   // 8^-0.5 * log2(e), folded into Q

// ---------------------------------------------------------------------------
// Kernel 1a: Q+K projections. 256 WGs (4 st x 64 chunks of 128 gp). (r12)
// ---------------------------------------------------------------------------
__global__ __launch_bounds__(256) void proj_qk_kernel(
    const float* __restrict__ x1, const float* __restrict__ x2,
    const float* __restrict__ Wq, const float* __restrict__ bq,
    const float* __restrict__ gq, const float* __restrict__ beq,
    const float* __restrict__ Wk, const float* __restrict__ bk,
    const float* __restrict__ gk, const float* __restrict__ bek,
    unsigned short* __restrict__ Qb, unsigned short* __restrict__ Kb)
{
    __shared__ __align__(16) float xs[128][68];
    const int wg = blockIdx.x, st = wg >> 6, chunk = wg & 63;
    const int lgP = 13 - 2*st, Pm1 = (1<<lgP) - 1;
    const int hb = 6 - st, wlm = (1<<hb) - 1;
    const int t = threadIdx.x;
    const int gp0 = chunk*128;
    const int blk = gp0 >> lgP, p0 = gp0 & Pm1;
    const int si = blk >> st, sj = blk & ((1<<st)-1);
    const int hwbase = ((si<<hb)<<6) | (sj<<hb);

    for (int idx = t; idx < 8192; idx += 256) {
        int c = idx >> 7, g = idx & 127;
        int p = p0 + g, half = p & 1, pw = p >> 1;
        int hw = hwbase | ((pw>>hb)<<6) | (pw & wlm);
        xs[g][c] = (half ? x2 : x1)[c*4096 + hw];
    }
    __syncthreads();

    const int g = t & 127, qk = t >> 7;          // wave-uniform qk
    const int gp = gp0 + g;
    float xr[64];
    #pragma unroll
    for (int q4 = 0; q4 < 16; ++q4)
        *(float4*)&xr[q4*4] = *(const float4*)&xs[g][q4*4];

    const float* Wb  = qk ? Wk  : Wq;
    const float* bb  = qk ? bk  : bq;
    const float* gb  = qk ? gk  : gq;
    const float* beb = qk ? bek : beq;
    unsigned short outv[8];
    for (int ch = 0; ch < 8; ++ch) {
        const float* wp = Wb + (st*8 + ch)*64;
        float d = 0.f;
        #pragma unroll
        for (int k = 0; k < 64; ++k) d += wp[k]*xr[k];
        float gm = gb[st*8+ch];
        float val = gm*(d + bb[st*8+ch]) + beb[st*8+ch];
        if (!qk) val *= QMUL;
        outv[ch] = f2bf(val);
    }
    unsigned short* dst = (qk ? Kb : Qb) + st*65536 + gp*8;
    *(uint4*)dst = *(uint4*)outv;
}

// ---------------------------------------------------------------------------
// Kernel 1b: V projection, tiled. 256 WGs. (r12)
// ---------------------------------------------------------------------------
__global__ __launch_bounds__(256) void proj_v_kernel(
    const float* __restrict__ x1, const float* __restrict__ x2,
    const float* __restrict__ Wv, const float* __restrict__ bv,
    unsigned short* __restrict__ Vf)
{
    __shared__ __align__(16) float xs[128][68];
    __shared__ __align__(16) unsigned short vout[64][128];
    const int wg = blockIdx.x, st = wg >> 6, chunk = wg & 63;
    const int lgP = 13 - 2*st, Pm1 = (1<<lgP) - 1;
    const int hb = 6 - st, wlm = (1<<hb) - 1;
    const int t = threadIdx.x;
    const int gp0 = chunk*128;
    const int blk = gp0 >> lgP, p0 = gp0 & Pm1;
    const int si = blk >> st, sj = blk & ((1<<st)-1);
    const int hwbase = ((si<<hb)<<6) | (sj<<hb);

    for (int idx = t; idx < 8192; idx += 256) {
        int c = idx >> 7, g = idx & 127;
        int p = p0 + g, half = p & 1, pw = p >> 1;
        int hw = hwbase | ((pw>>hb)<<6) | (pw & wlm);
        xs[g][c] = (half ? x2 : x1)[c*4096 + hw];
    }
    __syncthreads();

    const int g = t & 127, chh = (t >> 7) * 32;   // wave-uniform ch-half
    float xr[64];
    #pragma unroll
    for (int q4 = 0; q4 < 16; ++q4)
        *(float4*)&xr[q4*4] = *(const float4*)&xs[g][q4*4];

    for (int cc = 0; cc < 32; ++cc) {
        int ch = chh + cc;
        const float* wp = Wv + (st*64 + ch)*64;
        float d = bv[st*64 + ch];
        #pragma unroll
        for (int k = 0; k < 64; ++k) d += wp[k]*xr[k];
        vout[ch][g] = f2bf(d);
    }
    __syncthreads();

    unsigned short* Vst = Vf + st*524288 + (blk << (lgP+6));
    #pragma unroll
    for (int r = 0; r < 4; ++r) {
        int tt = t + r*256;
        int ch = tt >> 4, o = tt & 15;
        *(uint4*)(Vst + (ch << lgP) + p0 + o*8) = *(const uint4*)&vout[ch][o*8];
    }
}

// ---------------------------------------------------------------------------
// Kernel 2: barrier-free MFMA attention. 1536 WGs x 256 threads.
//   wg<512  : st0: qt=wg>>1, slot=wg&1;  wave keys = slot*4096+wv*1024, 1024
//   wg<1024 : st1: r=wg-512: qt=r>>1, slot=2+(r&1); keys=(r&1)*1024+wv*256, 256
//   wg<1280 : st2: qt=wg-1024, slot=4; keys=wv*128, 128
//   else    : st3: qt=wg-1280, slot=5; keys=wv*64, 64 (waves 2,3 idle)
// blk = qt >> (lgP-5); q0 = (qt & (P/32-1))*32. All 4 waves share the qtile.
// K/V B-frags read directly from global; per-wave P transpose via LDS;
// end-of-WG LDS tree merge (3 barriers) -> coalesced PART/LPART stores.
// ---------------------------------------------------------------------------
__global__ __launch_bounds__(256) void attn_kernel(
    const unsigned short* __restrict__ Qb, const unsigned short* __restrict__ Kb,
    const unsigned short* __restrict__ Vf,
    float* __restrict__ PART, float* __restrict__ LPART)
{
    __shared__ __align__(16) unsigned short Ps[4][2304];    // [q32][72]/wave; reused as merge bufs

    const int wg = blockIdx.x;
    const int t = threadIdx.x, lane = t & 63, wv = t >> 6;
    const int l31 = lane & 31, lhi = lane >> 5;

    int st, qt, slot, kbase, nkw;
    if (wg < 512)       { st=0; qt=wg>>1;  slot=wg&1;
                          kbase=(wg&1)*4096 + wv*1024; nkw=1024; }
    else if (wg < 1024) { int r=wg-512;  st=1; qt=r>>1; slot=2+(r&1);
                          kbase=(r&1)*1024 + wv*256;  nkw=256; }
    else if (wg < 1280) { st=2; qt=wg-1024; slot=4; kbase=wv*128; nkw=128; }
    else                { st=3; qt=wg-1280; slot=5; kbase=wv*64;
                          nkw=(wv<2)?64:0; }

    const int lgP = 13 - 2*st, P = 1 << lgP;
    const int blk = qt >> (lgP - 5);
    const int q0  = (qt & ((P>>5)-1)) * 32;

    const unsigned short* Qg = Qb + st*65536 + blk*P*8;
    const unsigned short* Kg = Kb + st*65536 + blk*P*8;
    const unsigned short* Vg = Vf + st*524288 + blk*P*64;   // [ch][p]

    bf16x8 qa;
    #pragma unroll
    for (int j = 0; j < 8; ++j) qa[j] = 0;
    if (lane < 32) qa = *(const bf16x8*)(Qg + (q0 + l31)*8);

    f32x16 acc0, acc1;
    #pragma unroll
    for (int r = 0; r < 16; ++r) { acc0[r] = 0.f; acc1[r] = 0.f; }
    float lsum_reg = 0.f;

    unsigned short* Pw = Ps[wv];
    for (int k0 = kbase; k0 < kbase + nkw; k0 += 64) {
        // K B-frags direct from global (lanes 32-63 broadcast; A pad is 0)
        bf16x8 kb0 = *(const bf16x8*)(Kg + (k0 + l31)*8);
        bf16x8 kb1 = *(const bf16x8*)(Kg + (k0 + 32 + l31)*8);
        f32x16 S0, S1;
        #pragma unroll
        for (int r = 0; r < 16; ++r) { S0[r] = 0.f; S1[r] = 0.f; }
        S0 = __builtin_amdgcn_mfma_f32_32x32x16_bf16(qa, kb0, S0, 0, 0, 0);
        S1 = __builtin_amdgcn_mfma_f32_32x32x16_bf16(qa, kb1, S1, 0, 0, 0);

        // exp2 -> bf16 -> per-wave LDS transpose (C-layout -> A-layout)
        #pragma unroll
        for (int r = 0; r < 16; ++r) {
            int qrow = (r&3) + 8*(r>>2) + 4*lhi;
            Pw[qrow*72 + l31]      = f2bf(exp2fast(S0[r]));
            Pw[qrow*72 + 32 + l31] = f2bf(exp2fast(S1[r]));
        }

        float lpart = 0.f;
        bf16x8 pa[4];
        #pragma unroll
        for (int kc = 0; kc < 4; ++kc) {
            pa[kc] = *(const bf16x8*)(Pw + l31*72 + kc*16 + 8*lhi);
            #pragma unroll
            for (int j = 0; j < 8; ++j)
                lpart += bf2f((unsigned short)pa[kc][j]);
        }
        lpart += __shfl_xor(lpart, 32, 64);
        lsum_reg += lpart;

        // V B-frags direct from global: 8 contiguous keys per lane
        #pragma unroll
        for (int kc = 0; kc < 4; ++kc) {
            const int ko = k0 + kc*16 + 8*lhi;
            bf16x8 vb0 = *(const bf16x8*)(Vg + l31*P + ko);
            bf16x8 vb1 = *(const bf16x8*)(Vg + (32 + l31)*P + ko);
            acc0 = __builtin_amdgcn_mfma_f32_32x32x16_bf16(pa[kc], vb0, acc0, 0, 0, 0);
            acc1 = __builtin_amdgcn_mfma_f32_32x32x16_bf16(pa[kc], vb1, acc1, 0, 0, 0);
        }
    }

    // ---- intra-WG merge of the 4 wave partials (LDS tree, reusing Ps) ----
    float* B0 = (float*)&Ps[0][0];        // 2048 fl
    float* B1 = B0 + 2048;                // 2048 fl (within Ps's 18432 B)
    float* Lm = B0 + 4096;                // 64 fl
    __syncthreads();                      // all waves done with Ps reads
    if (wv == 0 || wv == 2) {
        float* B = (wv == 0) ? B0 : B1;
        #pragma unroll
        for (int r = 0; r < 16; ++r) {
            int qrow = (r&3) + 8*(r>>2) + 4*lhi;
            B[qrow*64 + l31]      = acc0[r];
            B[qrow*64 + 32 + l31] = acc1[r];
        }
        if (lane < 32) Lm[(wv>>1)*32 + l31] = lsum_reg;
    }
    __syncthreads();
    if (wv == 1 || wv == 3) {
        float* B = (wv == 1) ? B0 : B1;
        #pragma unroll
        for (int r = 0; r < 16; ++r) {
            int qrow = (r&3) + 8*(r>>2) + 4*lhi;
            B[qrow*64 + l31]      += acc0[r];
            B[qrow*64 + 32 + l31] += acc1[r];
        }
        if (lane < 32) Lm[(wv>>1)*32 + l31] += lsum_reg;
    }
    __syncthreads();

    // coalesced stores: 2048 fl = 512 float4, all 256 threads
    float4* Pslab4 = (float4*)(PART + slot*524288 + qt*2048);
    const float4* B04 = (const float4*)B0;
    const float4* B14 = (const float4*)B1;
    #pragma unroll
    for (int r = 0; r < 2; ++r) {
        int idx = t + r*256;
        float4 a = B04[idx], b = B14[idx];
        Pslab4[idx] = float4{a.x+b.x, a.y+b.y, a.z+b.z, a.w+b.w};
    }
    if (t < 32)
        LPART[slot*8192 + qt*32 + t] = Lm[t] + Lm[32 + t];
}

// ---------------------------------------------------------------------------
// Kernel 3: sum partial slabs, normalize, final 1x1 conv (256->64). (r12)
// ---------------------------------------------------------------------------
__global__ __launch_bounds__(256) void normconv_kernel(
    const float* __restrict__ PART, const float* __restrict__ LPART,
    const float* __restrict__ Wo, float* __restrict__ out)
{
    __shared__ float cs[256][33];
    __shared__ float linv[4][32];
    __shared__ int gpar[4][32];
    const int t = threadIdx.x;
    const int px0 = blockIdx.x * 32;

    if (t < 128) {
        const int s0tab[4] = {0,2,4,5};
        const int sctab[4] = {2,2,1,1};
        int stt = t >> 5, i = t & 31;
        int pix = px0 + i;
        int half = pix >> 12, hw = pix & 4095;
        int h = hw >> 6, w = hw & 63;
        int hb = 6 - stt, wlm = (1<<hb)-1;
        int si = h >> hb, sj = w >> hb, hi = h & wlm, wi = w & wlm;
        int blk = (si << stt) | sj;
        int p = (((hi << hb) | wi) << 1) | half;
        int gp = blk*(8192>>(2*stt)) + p;
        gpar[stt][i] = gp;
        int s0 = s0tab[stt];
        float l = LPART[s0*8192 + gp];
        if (sctab[stt] == 2) l += LPART[(s0+1)*8192 + gp];
        linv[stt][i] = 1.f / l;
    }
    __syncthreads();

    for (int idx = t; idx < 256*32; idx += 256) {
        const int s0tab[4] = {0,2,4,5};
        const int sctab[4] = {2,2,1,1};
        int d = idx >> 5, i = idx & 31;        // d = st*64 + cv
        int stt = d >> 6, cv = d & 63;
        int gp = gpar[stt][i];
        int addr = (gp>>5)*2048 + (gp&31)*64 + cv;
        int s0 = s0tab[stt];
        float v = PART[s0*524288 + addr];
        if (sctab[stt] == 2) v += PART[(s0+1)*524288 + addr];
        cs[d][i] = v * linv[stt][i];
    }
    __syncthreads();

    const int i = t & 31;
    const int pix = px0 + i;
    const int half = pix >> 12, hw = pix & 4095;
    float* obase = out + half*262144 + hw;
    for (int oc = (t >> 5); oc < 64; oc += 8) {
        const float* wp = Wo + oc*256;
        float accv = 0.f;
        #pragma unroll 8
        for (int d = 0; d < 256; ++d) accv += wp[d]*cs[d][i];
        obase[oc*4096] = accv;
    }
}

// ---------------------------------------------------------------------------
extern "C" void kernel_launch(void* const* d_in, const int* in_sizes, int n_in,
                              void* d_out, int out_size, void* d_ws, size_t ws_size,
                              hipStream_t stream)
{
    (void)out_size; (void)ws_size;
    const float *x1, *x2, *Wq, *bq, *gq, *beq, *Wk, *bk, *gk, *bek, *Wv, *bv, *Wo;

    if (n_in >= 13 && in_sizes[0] == 2048) {       // sorted-key order (insurance)
        Wk  = (const float*)d_in[0];  Wo  = (const float*)d_in[1];
        Wq  = (const float*)d_in[2];  Wv  = (const float*)d_in[3];
        bek = (const float*)d_in[4];  beq = (const float*)d_in[5];
        bk  = (const float*)d_in[6];  bq  = (const float*)d_in[7];
        bv  = (const float*)d_in[8];  gk  = (const float*)d_in[9];
        gq  = (const float*)d_in[10];
        x1  = (const float*)d_in[11]; x2  = (const float*)d_in[12];
    } else {                                        // insertion order (proven)
        x1  = (const float*)d_in[0];  x2  = (const float*)d_in[1];
        Wq  = (const float*)d_in[2];  bq  = (const float*)d_in[3];
        gq  = (const float*)d_in[4];  beq = (const float*)d_in[5];
        Wk  = (const float*)d_in[6];  bk  = (const float*)d_in[7];
        gk  = (const float*)d_in[8];  bek = (const float*)d_in[9];
        Wv  = (const float*)d_in[10]; bv  = (const float*)d_in[11];
        Wo  = (const float*)d_in[12];
    }

    unsigned short* Qb = (unsigned short*)d_ws;     // 262144 ush
    unsigned short* Kb = Qb + 262144;               // 262144 ush
    unsigned short* Vf = Kb + 262144;               // 2097152 ush
    float* PART  = (float*)d_ws + 1310720;          // 3145728 fl
    float* LPART = PART + 3145728;                  // 49152 fl

    proj_qk_kernel<<<256, 256, 0, stream>>>(x1,x2,Wq,bq,gq,beq,Wk,bk,gk,bek,Qb,Kb);
    proj_v_kernel<<<256, 256, 0, stream>>>(x1,x2,Wv,bv,Vf);
    attn_kernel<<<1536, 256, 0, stream>>>(Qb,Kb,Vf,PART,LPART);
    normconv_kernel<<<256, 256, 0, stream>>>(PART, LPART, Wo, (float*)d_out);
}

// Round 14
// 165.053 us; speedup vs baseline: 3.6104x; 1.3031x over previous
//
#include <hip/hip_runtime.h>

// ---------------------------------------------------------------------------
// StaNet PAM — round 14: scalarized fused projections + MFMA normconv.
// attn_kernel byte-identical to r13 (passed, 58 us). PART/LPART/Qb/Kb/Vf
// formats unchanged.
//
// Workspace (float offsets), total 18.02 MB:
//   Qb   @ ush 0       : 262144 ush  [st][gp][ch] bf16 (Q pre-scaled QMUL)
//   Kb   @ ush 262144  : 262144 ush  [st][gp][ch] bf16
//   Vf   @ ush 524288  : 2097152 ush [st][blk][ch][p] bf16
//   PART @ fl  1310720 : 6*524288 fl [slot][tile][qrow32][ch64]
//   LPART@ fl  4456448 : 6*8192 fl   [slot][gp]
// slots: 0,1 = st0 splits; 2,3 = st1 splits; 4 = st2; 5 = st3. tile == qt.
// gp = blk*P + p; pix = half*4096 + h*64 + w; p = (((hi<<hb)|wi)<<1)|half.
// MFMA 32x32x16 bf16: A[m][k] m=lane&31,k=8*(lane>>5)+j; B[k][n] n=lane&31;
// C/D col=lane&31, row=(reg&3)+8*(reg>>2)+4*(lane>>5).
// ---------------------------------------------------------------------------

typedef short bf16x8 __attribute__((ext_vector_type(8)));
typedef float f32x16 __attribute__((ext_vector_type(16)));

__device__ __forceinline__ float bf2f(unsigned short u){ union{unsigned int i;float f;}v; v.i=((unsigned int)u)<<16; return v.f; }
__device__ __forceinline__ unsigned short f2bf(float f){
    union{float f;unsigned int i;}v; v.f=f;
    unsigned int r = v.i + 0x7fffu + ((v.i>>16)&1u);
    return (unsigned short)(r>>16);
}
__device__ __forceinline__ float exp2fast(float x){ return __builtin_amdgcn_exp2f(x); }

#define QMUL 0.5100697233f   // 8^-0.5 * log2(e), folded into Q

// ---------------------------------------------------------------------------
// Kernel 1: fused Q/K/V projection. 512 WGs (4 st x 128 chunks of 64 gp).
// Wave-uniform channel ranges -> weights scalarize to s_loads.
//   w0: Q ch0-7, K ch0-7, V ch0-3;  w1: V4-23;  w2: V24-43;  w3: V44-63.
// ---------------------------------------------------------------------------
__global__ __launch_bounds__(256) void proj_all_kernel(
    const float* __restrict__ x1, const float* __restrict__ x2,
    const float* __restrict__ Wq, const float* __restrict__ bq,
    const float* __restrict__ gq, const float* __restrict__ beq,
    const float* __restrict__ Wk, const float* __restrict__ bk,
    const float* __restrict__ gk, const float* __restrict__ bek,
    const float* __restrict__ Wv, const float* __restrict__ bv,
    unsigned short* __restrict__ Qb, unsigned short* __restrict__ Kb,
    unsigned short* __restrict__ Vf)
{
    __shared__ __align__(16) float xs[64][68];
    __shared__ __align__(16) unsigned int vqk[64][8];   // [px][0-3 Qpairs|4-7 Kpairs]
    __shared__ __align__(16) unsigned short vv[64][64]; // [ch][px]

    const int wg = blockIdx.x, st = wg >> 7, chunk = wg & 127;
    const int lgP = 13 - 2*st, Pm1 = (1<<lgP) - 1;
    const int hb = 6 - st, wlm = (1<<hb) - 1;
    const int t = threadIdx.x;
    const int gp0 = chunk*64;
    const int blk = gp0 >> lgP, p0 = gp0 & Pm1;
    const int si = blk >> st, sj = blk & ((1<<st)-1);
    const int hwbase = ((si<<hb)<<6) | (sj<<hb);

    for (int idx = t; idx < 4096; idx += 256) {
        int c = idx >> 6, g = idx & 63;
        int p = p0 + g, half = p & 1, pw = p >> 1;
        int hw = hwbase | ((pw>>hb)<<6) | (pw & wlm);
        xs[g][c] = (half ? x2 : x1)[c*4096 + hw];
    }
    __syncthreads();

    const int px = t & 63, wv = t >> 6;
    float xr[64];
    #pragma unroll
    for (int q4 = 0; q4 < 16; ++q4)
        *(float4*)&xr[q4*4] = *(const float4*)&xs[px][q4*4];

#define VRANGE(LO,HI)                                              \
    for (int ch = (LO); ch < (HI); ++ch) {                         \
        const float* wp = Wv + (st*64 + ch)*64;                    \
        float d = bv[st*64 + ch];                                  \
        _Pragma("unroll")                                          \
        for (int k = 0; k < 64; ++k) d += wp[k]*xr[k];             \
        vv[ch][px] = f2bf(d);                                      \
    }

    if (wv == 0) {
        unsigned short qo[8], ko[8];
        for (int ch = 0; ch < 8; ++ch) {
            const float* wp = Wq + (st*8 + ch)*64;
            float d = 0.f;
            #pragma unroll
            for (int k = 0; k < 64; ++k) d += wp[k]*xr[k];
            float gm = gq[st*8+ch];
            qo[ch] = f2bf((gm*(d + bq[st*8+ch]) + beq[st*8+ch])*QMUL);
        }
        for (int ch = 0; ch < 8; ++ch) {
            const float* wp = Wk + (st*8 + ch)*64;
            float d = 0.f;
            #pragma unroll
            for (int k = 0; k < 64; ++k) d += wp[k]*xr[k];
            float gm = gk[st*8+ch];
            ko[ch] = f2bf(gm*(d + bk[st*8+ch]) + bek[st*8+ch]);
        }
        #pragma unroll
        for (int i = 0; i < 4; ++i) {
            vqk[px][i]   = (unsigned)qo[2*i] | ((unsigned)qo[2*i+1] << 16);
            vqk[px][4+i] = (unsigned)ko[2*i] | ((unsigned)ko[2*i+1] << 16);
        }
        VRANGE(0, 4)
    } else if (wv == 1) { VRANGE(4, 24) }
    else if   (wv == 2) { VRANGE(24, 44) }
    else                { VRANGE(44, 64) }
#undef VRANGE
    __syncthreads();

    if (t < 64) {
        *(uint4*)(Qb + st*65536 + (gp0 + t)*8) = *(const uint4*)&vqk[t][0];
    } else if (t < 128) {
        int p2 = t - 64;
        *(uint4*)(Kb + st*65536 + (gp0 + p2)*8) = *(const uint4*)&vqk[p2][4];
    }
    unsigned short* Vst = Vf + st*524288 + (blk << (lgP+6));
    #pragma unroll
    for (int r = 0; r < 2; ++r) {
        int task = t + r*256;           // 512 uint4 tasks
        int ch = task >> 3, o = task & 7;
        *(uint4*)(Vst + (ch << lgP) + p0 + o*8) = *(const uint4*)&vv[ch][o*8];
    }
}

// ---------------------------------------------------------------------------
// Kernel 2: barrier-free MFMA attention. 1536 WGs x 256 threads. (r13)
// ---------------------------------------------------------------------------
__global__ __launch_bounds__(256) void attn_kernel(
    const unsigned short* __restrict__ Qb, const unsigned short* __restrict__ Kb,
    const unsigned short* __restrict__ Vf,
    float* __restrict__ PART, float* __restrict__ LPART)
{
    __shared__ __align__(16) unsigned short Ps[4][2304];

    const int wg = blockIdx.x;
    const int t = threadIdx.x, lane = t & 63, wv = t >> 6;
    const int l31 = lane & 31, lhi = lane >> 5;

    int st, qt, slot, kbase, nkw;
    if (wg < 512)       { st=0; qt=wg>>1;  slot=wg&1;
                          kbase=(wg&1)*4096 + wv*1024; nkw=1024; }
    else if (wg < 1024) { int r=wg-512;  st=1; qt=r>>1; slot=2+(r&1);
                          kbase=(r&1)*1024 + wv*256;  nkw=256; }
    else if (wg < 1280) { st=2; qt=wg-1024; slot=4; kbase=wv*128; nkw=128; }
    else                { st=3; qt=wg-1280; slot=5; kbase=wv*64;
                          nkw=(wv<2)?64:0; }

    const int lgP = 13 - 2*st, P = 1 << lgP;
    const int blk = qt >> (lgP - 5);
    const int q0  = (qt & ((P>>5)-1)) * 32;

    const unsigned short* Qg = Qb + st*65536 + blk*P*8;
    const unsigned short* Kg = Kb + st*65536 + blk*P*8;
    const unsigned short* Vg = Vf + st*524288 + blk*P*64;

    bf16x8 qa;
    #pragma unroll
    for (int j = 0; j < 8; ++j) qa[j] = 0;
    if (lane < 32) qa = *(const bf16x8*)(Qg + (q0 + l31)*8);

    f32x16 acc0, acc1;
    #pragma unroll
    for (int r = 0; r < 16; ++r) { acc0[r] = 0.f; acc1[r] = 0.f; }
    float lsum_reg = 0.f;

    unsigned short* Pw = Ps[wv];
    for (int k0 = kbase; k0 < kbase + nkw; k0 += 64) {
        bf16x8 kb0 = *(const bf16x8*)(Kg + (k0 + l31)*8);
        bf16x8 kb1 = *(const bf16x8*)(Kg + (k0 + 32 + l31)*8);
        f32x16 S0, S1;
        #pragma unroll
        for (int r = 0; r < 16; ++r) { S0[r] = 0.f; S1[r] = 0.f; }
        S0 = __builtin_amdgcn_mfma_f32_32x32x16_bf16(qa, kb0, S0, 0, 0, 0);
        S1 = __builtin_amdgcn_mfma_f32_32x32x16_bf16(qa, kb1, S1, 0, 0, 0);

        #pragma unroll
        for (int r = 0; r < 16; ++r) {
            int qrow = (r&3) + 8*(r>>2) + 4*lhi;
            Pw[qrow*72 + l31]      = f2bf(exp2fast(S0[r]));
            Pw[qrow*72 + 32 + l31] = f2bf(exp2fast(S1[r]));
        }

        float lpart = 0.f;
        bf16x8 pa[4];
        #pragma unroll
        for (int kc = 0; kc < 4; ++kc) {
            pa[kc] = *(const bf16x8*)(Pw + l31*72 + kc*16 + 8*lhi);
            #pragma unroll
            for (int j = 0; j < 8; ++j)
                lpart += bf2f((unsigned short)pa[kc][j]);
        }
        lpart += __shfl_xor(lpart, 32, 64);
        lsum_reg += lpart;

        #pragma unroll
        for (int kc = 0; kc < 4; ++kc) {
            const int ko = k0 + kc*16 + 8*lhi;
            bf16x8 vb0 = *(const bf16x8*)(Vg + l31*P + ko);
            bf16x8 vb1 = *(const bf16x8*)(Vg + (32 + l31)*P + ko);
            acc0 = __builtin_amdgcn_mfma_f32_32x32x16_bf16(pa[kc], vb0, acc0, 0, 0, 0);
            acc1 = __builtin_amdgcn_mfma_f32_32x32x16_bf16(pa[kc], vb1, acc1, 0, 0, 0);
        }
    }

    float* B0 = (float*)&Ps[0][0];
    float* B1 = B0 + 2048;
    float* Lm = B0 + 4096;
    __syncthreads();
    if (wv == 0 || wv == 2) {
        float* B = (wv == 0) ? B0 : B1;
        #pragma unroll
        for (int r = 0; r < 16; ++r) {
            int qrow = (r&3) + 8*(r>>2) + 4*lhi;
            B[qrow*64 + l31]      = acc0[r];
            B[qrow*64 + 32 + l31] = acc1[r];
        }
        if (lane < 32) Lm[(wv>>1)*32 + l31] = lsum_reg;
    }
    __syncthreads();
    if (wv == 1 || wv == 3) {
        float* B = (wv == 1) ? B0 : B1;
        #pragma unroll
        for (int r = 0; r < 16; ++r) {
            int qrow = (r&3) + 8*(r>>2) + 4*lhi;
            B[qrow*64 + l31]      += acc0[r];
            B[qrow*64 + 32 + l31] += acc1[r];
        }
        if (lane < 32) Lm[(wv>>1)*32 + l31] += lsum_reg;
    }
    __syncthreads();

    float4* Pslab4 = (float4*)(PART + slot*524288 + qt*2048);
    const float4* B04 = (const float4*)B0;
    const float4* B14 = (const float4*)B1;
    #pragma unroll
    for (int r = 0; r < 2; ++r) {
        int idx = t + r*256;
        float4 a = B04[idx], b = B14[idx];
        Pslab4[idx] = float4{a.x+b.x, a.y+b.y, a.z+b.z, a.w+b.w};
    }
    if (t < 32)
        LPART[slot*8192 + qt*32 + t] = Lm[t] + Lm[32 + t];
}

// ---------------------------------------------------------------------------
// Kernel 3: normconv via MFMA. 256 WGs x 256 threads, 32 canonical px each.
// Coalesced PART gather (64-ch contiguous runs), ctx->bf16 LDS, Wo^T staged
// in B-frag order, waves = (oc-half x k-half), LDS merge, coalesced stores.
// ---------------------------------------------------------------------------
__global__ __launch_bounds__(256) void normconv_kernel(
    const float* __restrict__ PART, const float* __restrict__ LPART,
    const float* __restrict__ Wo, float* __restrict__ out)
{
    __shared__ __align__(16) unsigned short csb[32][264];   // ctx bf16 [px][256d]
    __shared__ __align__(16) unsigned short wof[16384];     // Wo^T frag order
    __shared__ float voutf[64][33];
    __shared__ float linv[4][32];
    __shared__ int gpar[4][32];
    const int t = threadIdx.x;
    const int px0 = blockIdx.x * 32;

    // Wo^T fragment staging: thread reads Wo[oc][d0..d0+63] coalesced.
    {
        int oc = t >> 2, d0 = (t & 3) * 64;
        for (int b = 0; b < 8; ++b) {
            int d = d0 + b*8;
            float4 w0 = *(const float4*)(Wo + oc*256 + d);
            float4 w1 = *(const float4*)(Wo + oc*256 + d + 4);
            unsigned short tmp[8];
            tmp[0]=f2bf(w0.x); tmp[1]=f2bf(w0.y); tmp[2]=f2bf(w0.z); tmp[3]=f2bf(w0.w);
            tmp[4]=f2bf(w1.x); tmp[5]=f2bf(w1.y); tmp[6]=f2bf(w1.z); tmp[7]=f2bf(w1.w);
            *(uint4*)&wof[(d>>3)*512 + oc*8] = *(const uint4*)tmp;
        }
    }
    if (t < 128) {
        const int s0tab[4] = {0,2,4,5};
        const int sctab[4] = {2,2,1,1};
        int stt = t >> 5, i = t & 31;
        int pix = px0 + i;
        int half = pix >> 12, hw = pix & 4095;
        int h = hw >> 6, w = hw & 63;
        int hb = 6 - stt, wlm = (1<<hb)-1;
        int si = h >> hb, sj = w >> hb, hi = h & wlm, wi = w & wlm;
        int blk = (si << stt) | sj;
        int p = (((hi << hb) | wi) << 1) | half;
        int gp = blk*(8192>>(2*stt)) + p;
        gpar[stt][i] = gp;
        int s0 = s0tab[stt];
        float l = LPART[s0*8192 + gp];
        if (sctab[stt] == 2) l += LPART[(s0+1)*8192 + gp];
        linv[stt][i] = 1.f / l;
    }
    __syncthreads();

    // ctx gather: thread = (px = t>>3, cvg = (t&7)*8): contiguous 64-ch runs.
    {
        const int s0tab[4] = {0,2,4,5};
        int gpx = t >> 3, cvg = (t & 7) * 8;
        for (int stt = 0; stt < 4; ++stt) {
            int gp = gpar[stt][gpx];
            const float* p = PART + s0tab[stt]*524288
                           + (gp>>5)*2048 + (gp&31)*64 + cvg;
            float4 a = *(const float4*)p;
            float4 b = *(const float4*)(p + 4);
            if (stt < 2) {
                float4 a2 = *(const float4*)(p + 524288);
                float4 b2 = *(const float4*)(p + 524288 + 4);
                a.x+=a2.x; a.y+=a2.y; a.z+=a2.z; a.w+=a2.w;
                b.x+=b2.x; b.y+=b2.y; b.z+=b2.z; b.w+=b2.w;
            }
            float li = linv[stt][gpx];
            unsigned short tmp[8];
            tmp[0]=f2bf(a.x*li); tmp[1]=f2bf(a.y*li); tmp[2]=f2bf(a.z*li); tmp[3]=f2bf(a.w*li);
            tmp[4]=f2bf(b.x*li); tmp[5]=f2bf(b.y*li); tmp[6]=f2bf(b.z*li); tmp[7]=f2bf(b.w*li);
            *(uint4*)&csb[gpx][stt*64 + cvg] = *(const uint4*)tmp;
        }
    }
    __syncthreads();

    // MFMA: wave = (nh = wv&1 oc-half, kh = wv>>1 k-half), 8 K-steps each.
    const int lane = t & 63, wvv = t >> 6;
    const int l31 = lane & 31, lhi = lane >> 5;
    const int nh = wvv & 1, kh = wvv >> 1;
    f32x16 acc;
    #pragma unroll
    for (int r = 0; r < 16; ++r) acc[r] = 0.f;
    #pragma unroll
    for (int s = 0; s < 8; ++s) {
        int dg = kh*16 + s*2 + lhi;                       // d>>3 group
        bf16x8 a = *(const bf16x8*)&csb[l31][kh*128 + s*16 + 8*lhi];
        bf16x8 b = *(const bf16x8*)&wof[dg*512 + (nh*32 + l31)*8];
        acc = __builtin_amdgcn_mfma_f32_32x32x16_bf16(a, b, acc, 0, 0, 0);
    }
    if (kh == 0) {
        #pragma unroll
        for (int r = 0; r < 16; ++r)
            voutf[nh*32 + l31][(r&3) + 8*(r>>2) + 4*lhi] = acc[r];
    }
    __syncthreads();
    if (kh == 1) {
        #pragma unroll
        for (int r = 0; r < 16; ++r)
            voutf[nh*32 + l31][(r&3) + 8*(r>>2) + 4*lhi] += acc[r];
    }
    __syncthreads();

    const int half = px0 >> 12, hw0 = px0 & 4095;
    float* obase = out + half*262144 + hw0;
    #pragma unroll
    for (int r = 0; r < 8; ++r) {
        int idx = t + r*256;
        int oc = idx >> 5, pxi = idx & 31;
        obase[oc*4096 + pxi] = voutf[oc][pxi];
    }
}

// ---------------------------------------------------------------------------
extern "C" void kernel_launch(void* const* d_in, const int* in_sizes, int n_in,
                              void* d_out, int out_size, void* d_ws, size_t ws_size,
                              hipStream_t stream)
{
    (void)out_size; (void)ws_size;
    const float *x1, *x2, *Wq, *bq, *gq, *beq, *Wk, *bk, *gk, *bek, *Wv, *bv, *Wo;

    if (n_in >= 13 && in_sizes[0] == 2048) {       // sorted-key order (insurance)
        Wk  = (const float*)d_in[0];  Wo  = (const float*)d_in[1];
        Wq  = (const float*)d_in[2];  Wv  = (const float*)d_in[3];
        bek = (const float*)d_in[4];  beq = (const float*)d_in[5];
        bk  = (const float*)d_in[6];  bq  = (const float*)d_in[7];
        bv  = (const float*)d_in[8];  gk  = (const float*)d_in[9];
        gq  = (const float*)d_in[10];
        x1  = (const float*)d_in[11]; x2  = (const float*)d_in[12];
    } else {                                        // insertion order (proven)
        x1  = (const float*)d_in[0];  x2  = (const float*)d_in[1];
        Wq  = (const float*)d_in[2];  bq  = (const float*)d_in[3];
        gq  = (const float*)d_in[4];  beq = (const float*)d_in[5];
        Wk  = (const float*)d_in[6];  bk  = (const float*)d_in[7];
        gk  = (const float*)d_in[8];  bek = (const float*)d_in[9];
        Wv  = (const float*)d_in[10]; bv  = (const float*)d_in[11];
        Wo  = (const float*)d_in[12];
    }

    unsigned short* Qb = (unsigned short*)d_ws;     // 262144 ush
    unsigned short* Kb = Qb + 262144;               // 262144 ush
    unsigned short* Vf = Kb + 262144;               // 2097152 ush
    float* PART  = (float*)d_ws + 1310720;          // 3145728 fl
    float* LPART = PART + 3145728;                  // 49152 fl

    proj_all_kernel<<<512, 256, 0, stream>>>(x1,x2,Wq,bq,gq,beq,Wk,bk,gk,bek,Wv,bv,Qb,Kb,Vf);
    attn_kernel<<<1536, 256, 0, stream>>>(Qb,Kb,Vf,PART,LPART);
    normconv_kernel<<<256, 256, 0, stream>>>(PART, LPART, Wo, (float*)d_out);
}